// Round 1
// baseline (2641.478 us; speedup 1.0000x reference)
//
#include <hip/hip_runtime.h>
#include <math.h>

#define NB   2
#define SEQ  2048
#define CDIM 512
#define HID  1024
#define NH   16
#define HD   64
// ROTARY_DIM = 16, half = 8

// ---------------------------------------------------------------------------
// QKV projection: context (4096 x 512) @ W (512 x 1024) + b, scattered into
// (B, NH, S, D) layout. blockIdx.z selects q/k/v.
// 128x128 tile, BK=8, 256 threads, 8x8 micro-tile.
// ---------------------------------------------------------------------------
__global__ __launch_bounds__(256)
void qkv_gemm(const float* __restrict__ ctx,
              const float* __restrict__ Wq, const float* __restrict__ bq,
              const float* __restrict__ Wk, const float* __restrict__ bk,
              const float* __restrict__ Wv, const float* __restrict__ bv,
              float* __restrict__ qo, float* __restrict__ ko, float* __restrict__ vo)
{
    const int z = blockIdx.z;
    const float* __restrict__ W    = (z == 0) ? Wq : ((z == 1) ? Wk : Wv);
    const float* __restrict__ bias = (z == 0) ? bq : ((z == 1) ? bk : bv);
    float* __restrict__ out        = (z == 0) ? qo : ((z == 1) ? ko : vo);

    __shared__ float As[8][128];
    __shared__ float Bs[8][128];

    const int tid = threadIdx.x;
    const int bm = blockIdx.x * 128;
    const int bn = blockIdx.y * 128;
    const int tx = tid & 15;        // 16 col-groups
    const int ty = tid >> 4;        // 16 row-groups
    const int am  = tid >> 1;       // A-load row (0..127)
    const int ak  = (tid & 1) * 4;  // A-load k offset (0 or 4)
    const int bkr = tid >> 5;       // B-load k row (0..7)
    const int bn4 = (tid & 31) * 4; // B-load col (0..124)

    float acc[8][8] = {};

    for (int k0 = 0; k0 < CDIM; k0 += 8) {
        const float4 av  = *(const float4*)&ctx[(size_t)(bm + am) * CDIM + k0 + ak];
        const float4 bv4 = *(const float4*)&W[(size_t)(k0 + bkr) * HID + bn + bn4];
        As[ak + 0][am] = av.x; As[ak + 1][am] = av.y;
        As[ak + 2][am] = av.z; As[ak + 3][am] = av.w;
        *(float4*)&Bs[bkr][bn4] = bv4;
        __syncthreads();
        #pragma unroll
        for (int kk = 0; kk < 8; kk++) {
            float a[8], b[8];
            *(float4*)&a[0] = *(const float4*)&As[kk][ty * 8];
            *(float4*)&a[4] = *(const float4*)&As[kk][ty * 8 + 4];
            *(float4*)&b[0] = *(const float4*)&Bs[kk][tx * 8];
            *(float4*)&b[4] = *(const float4*)&Bs[kk][tx * 8 + 4];
            #pragma unroll
            for (int i = 0; i < 8; i++)
                #pragma unroll
                for (int j = 0; j < 8; j++)
                    acc[i][j] = fmaf(a[i], b[j], acc[i][j]);
        }
        __syncthreads();
    }

    // scatter epilogue: row m -> (b, s); col n -> (h, d); write (B,NH,S,D)
    #pragma unroll
    for (int i = 0; i < 8; i++) {
        const int m  = bm + ty * 8 + i;
        const int b_ = m >> 11;          // / 2048
        const int s  = m & (SEQ - 1);
        #pragma unroll
        for (int j = 0; j < 8; j++) {
            const int n = bn + tx * 8 + j;
            const int h = n >> 6, d = n & 63;
            out[(((size_t)(b_ * NH + h)) * SEQ + s) * HD + d] = acc[i][j] + bias[n];
        }
    }
}

// ---------------------------------------------------------------------------
// In-place RoPE on first 16 dims of each head of q and k.
// One thread per (tensor, b, h, s, freq-pair i in 0..7).
// ---------------------------------------------------------------------------
__global__ __launch_bounds__(256)
void rope_kernel(float* __restrict__ q, float* __restrict__ k)
{
    const int idx = blockIdx.x * 256 + threadIdx.x;
    const int per = NB * NH * SEQ * 8;   // 524288
    float* x;
    int r;
    if (idx < per) { x = q; r = idx; } else { x = k; r = idx - per; }
    const int i  = r & 7;
    const int s  = (r >> 3) & (SEQ - 1);
    const int bh = r >> 14;              // 8*2048 = 2^14
    float* p = x + ((size_t)bh * SEQ + s) * HD;
    // inv_freq = 10000^(-i/8) = 2^(-i/8 * log2(10000))
    const float inv_freq = exp2f((float)i * (-13.287712379549449f / 8.0f));
    float sn, cs;
    sincosf((float)s * inv_freq, &sn, &cs);
    const float x1 = p[i], x2 = p[i + 8];
    p[i]     = fmaf(x1, cs, -x2 * sn);
    p[i + 8] = fmaf(x2, cs,  x1 * sn);
}

// ---------------------------------------------------------------------------
// Flash-style causal attention. Block = 256 threads = 4 waves; each wave owns
// 4 consecutive q-rows (16 rows/block). K staged padded (65) so lane-indexed
// row reads are conflict-free; V staged unpadded for lane-d coalesced reads.
// Online softmax with -3e38 sentinel (no inf/NaN arithmetic anywhere).
// Output written to (B*S, NH, HD) row-major = (B, S, HID).
// ---------------------------------------------------------------------------
__global__ __launch_bounds__(256)
void attn_kernel(const float* __restrict__ qg, const float* __restrict__ kg,
                 const float* __restrict__ vg, float* __restrict__ out)
{
    __shared__ float Ks[64][65];
    __shared__ float Vs[64][64];
    const int tid  = threadIdx.x;
    const int lane = tid & 63;
    const int wv   = tid >> 6;
    const int tile = blockIdx.x;
    const int h    = blockIdx.y;
    const int b    = blockIdx.z;
    const int q0   = tile * 16;
    const size_t base = ((size_t)(b * NH + h)) * SEQ * HD;

    float qreg[4], acc[4], mrun[4], lrun[4];
    int qrow[4];
    #pragma unroll
    for (int r = 0; r < 4; r++) {
        qrow[r] = q0 + wv * 4 + r;
        qreg[r] = qg[base + (size_t)qrow[r] * HD + lane] * 0.125f; // fold 1/sqrt(64)
        acc[r] = 0.f; mrun[r] = -3.0e38f; lrun[r] = 0.f;
    }

    const int qmax = q0 + 15;
    for (int j0 = 0; j0 <= qmax; j0 += 64) {
        __syncthreads();
        #pragma unroll
        for (int w = 0; w < 4; w++) {
            const int i4 = tid + w * 256;       // float4 index 0..1023
            const int j  = i4 >> 4;
            const int d4 = (i4 & 15) << 2;
            const float4 kv = *(const float4*)&kg[base + (size_t)(j0 + j) * HD + d4];
            Ks[j][d4 + 0] = kv.x; Ks[j][d4 + 1] = kv.y;
            Ks[j][d4 + 2] = kv.z; Ks[j][d4 + 3] = kv.w;
            const float4 vv = *(const float4*)&vg[base + (size_t)(j0 + j) * HD + d4];
            *(float4*)&Vs[j][d4] = vv;
        }
        __syncthreads();

        // scores: lane computes key j0+lane for this wave's 4 rows
        float s[4] = {0.f, 0.f, 0.f, 0.f};
        #pragma unroll
        for (int d = 0; d < 64; d++) {
            const float kd = Ks[lane][d];
            #pragma unroll
            for (int r = 0; r < 4; r++)
                s[r] = fmaf(__shfl(qreg[r], d), kd, s[r]);
        }

        const int jkey = j0 + lane;
        float pr[4];
        #pragma unroll
        for (int r = 0; r < 4; r++) {
            const float sv = (jkey <= qrow[r]) ? s[r] : -3.0e38f;
            float mx = sv;
            #pragma unroll
            for (int off = 32; off; off >>= 1)
                mx = fmaxf(mx, __shfl_xor(mx, off));
            const float mn   = fmaxf(mrun[r], mx);
            const float p    = __expf(sv - mn);
            const float corr = __expf(mrun[r] - mn);
            float ps = p;
            #pragma unroll
            for (int off = 32; off; off >>= 1)
                ps += __shfl_xor(ps, off);
            lrun[r] = lrun[r] * corr + ps;
            mrun[r] = mn;
            acc[r] *= corr;
            pr[r] = p;
        }

        // PV: lane d accumulates over this key block
        #pragma unroll
        for (int j = 0; j < 64; j++) {
            const float vv = Vs[j][lane];
            #pragma unroll
            for (int r = 0; r < 4; r++)
                acc[r] = fmaf(__shfl(pr[r], j), vv, acc[r]);
        }
    }

    #pragma unroll
    for (int r = 0; r < 4; r++)
        out[(((size_t)(b * SEQ + qrow[r])) * NH + h) * HD + lane] = acc[r] / lrun[r];
}

// ---------------------------------------------------------------------------
// Output projection: attn (4096 x 1024) @ Wd (1024 x 1024) + bd -> d_out.
// ---------------------------------------------------------------------------
__global__ __launch_bounds__(256)
void proj_gemm(const float* __restrict__ A,
               const float* __restrict__ W, const float* __restrict__ bias,
               float* __restrict__ out)
{
    __shared__ float As[8][128];
    __shared__ float Bs[8][128];

    const int tid = threadIdx.x;
    const int bm = blockIdx.x * 128;
    const int bn = blockIdx.y * 128;
    const int tx = tid & 15;
    const int ty = tid >> 4;
    const int am  = tid >> 1;
    const int ak  = (tid & 1) * 4;
    const int bkr = tid >> 5;
    const int bn4 = (tid & 31) * 4;

    float acc[8][8] = {};

    for (int k0 = 0; k0 < HID; k0 += 8) {
        const float4 av  = *(const float4*)&A[(size_t)(bm + am) * HID + k0 + ak];
        const float4 bv4 = *(const float4*)&W[(size_t)(k0 + bkr) * HID + bn + bn4];
        As[ak + 0][am] = av.x; As[ak + 1][am] = av.y;
        As[ak + 2][am] = av.z; As[ak + 3][am] = av.w;
        *(float4*)&Bs[bkr][bn4] = bv4;
        __syncthreads();
        #pragma unroll
        for (int kk = 0; kk < 8; kk++) {
            float a[8], b[8];
            *(float4*)&a[0] = *(const float4*)&As[kk][ty * 8];
            *(float4*)&a[4] = *(const float4*)&As[kk][ty * 8 + 4];
            *(float4*)&b[0] = *(const float4*)&Bs[kk][tx * 8];
            *(float4*)&b[4] = *(const float4*)&Bs[kk][tx * 8 + 4];
            #pragma unroll
            for (int i = 0; i < 8; i++)
                #pragma unroll
                for (int j = 0; j < 8; j++)
                    acc[i][j] = fmaf(a[i], b[j], acc[i][j]);
        }
        __syncthreads();
    }

    #pragma unroll
    for (int i = 0; i < 8; i++) {
        const int m = bm + ty * 8 + i;
        #pragma unroll
        for (int j = 0; j < 8; j++) {
            const int n = bn + tx * 8 + j;
            out[(size_t)m * HID + n] = acc[i][j] + bias[n];
        }
    }
}

// ---------------------------------------------------------------------------
extern "C" void kernel_launch(void* const* d_in, const int* in_sizes, int n_in,
                              void* d_out, int out_size, void* d_ws, size_t ws_size,
                              hipStream_t stream)
{
    const float* ctx = (const float*)d_in[0];
    const float* Wq  = (const float*)d_in[1];
    const float* bq  = (const float*)d_in[2];
    const float* Wk  = (const float*)d_in[3];
    const float* bk  = (const float*)d_in[4];
    const float* Wv  = (const float*)d_in[5];
    const float* bv  = (const float*)d_in[6];
    const float* Wd  = (const float*)d_in[7];
    const float* bd  = (const float*)d_in[8];
    float* outp = (float*)d_out;

    // workspace: q, k, v in (B,NH,S,D) + attn in (B*S, HID); 64 MB fp32 total
    const size_t per = (size_t)NB * NH * SEQ * HD;  // 4,194,304 floats
    float* qw = (float*)d_ws;
    float* kw = qw + per;
    float* vw = kw + per;
    float* aw = vw + per;

    const dim3 blk(256);
    qkv_gemm <<<dim3(32, 8, 3),        blk, 0, stream>>>(ctx, Wq, bq, Wk, bk, Wv, bv, qw, kw, vw);
    rope_kernel<<<dim3(4096),          blk, 0, stream>>>(qw, kw);
    attn_kernel<<<dim3(SEQ/16, NH, NB), blk, 0, stream>>>(qw, kw, vw, aw);
    proj_gemm <<<dim3(32, 8),          blk, 0, stream>>>(aw, Wd, bd, outp);
}

// Round 4
// 1287.613 us; speedup vs baseline: 2.0515x; 2.0515x over previous
//
#include <hip/hip_runtime.h>
#include <math.h>

#define NB   2
#define SEQ  2048
#define CDIM 512
#define HID  1024
#define NH   16
#define HD   64
// ROTARY_DIM = 16, half = 8

// ---------------------------------------------------------------------------
// QKV projection: context (4096 x 512) @ W (512 x 1024) + b, scattered into
// (B, NH, S, D) layout. blockIdx.z selects q/k/v.
// 128x128 tile, BK=8, 256 threads, 8x8 micro-tile.
// ---------------------------------------------------------------------------
__global__ __launch_bounds__(256)
void qkv_gemm(const float* __restrict__ ctx,
              const float* __restrict__ Wq, const float* __restrict__ bq,
              const float* __restrict__ Wk, const float* __restrict__ bk,
              const float* __restrict__ Wv, const float* __restrict__ bv,
              float* __restrict__ qo, float* __restrict__ ko, float* __restrict__ vo)
{
    const int z = blockIdx.z;
    const float* __restrict__ W    = (z == 0) ? Wq : ((z == 1) ? Wk : Wv);
    const float* __restrict__ bias = (z == 0) ? bq : ((z == 1) ? bk : bv);
    float* __restrict__ out        = (z == 0) ? qo : ((z == 1) ? ko : vo);

    __shared__ float As[8][128];
    __shared__ float Bs[8][128];

    const int tid = threadIdx.x;
    const int bm = blockIdx.x * 128;
    const int bn = blockIdx.y * 128;
    const int tx = tid & 15;        // 16 col-groups
    const int ty = tid >> 4;        // 16 row-groups
    const int am  = tid >> 1;       // A-load row (0..127)
    const int ak  = (tid & 1) * 4;  // A-load k offset (0 or 4)
    const int bkr = tid >> 5;       // B-load k row (0..7)
    const int bn4 = (tid & 31) * 4; // B-load col (0..124)

    float acc[8][8] = {};

    for (int k0 = 0; k0 < CDIM; k0 += 8) {
        const float4 av  = *(const float4*)&ctx[(size_t)(bm + am) * CDIM + k0 + ak];
        const float4 bv4 = *(const float4*)&W[(size_t)(k0 + bkr) * HID + bn + bn4];
        As[ak + 0][am] = av.x; As[ak + 1][am] = av.y;
        As[ak + 2][am] = av.z; As[ak + 3][am] = av.w;
        *(float4*)&Bs[bkr][bn4] = bv4;
        __syncthreads();
        #pragma unroll
        for (int kk = 0; kk < 8; kk++) {
            float a[8], b[8];
            *(float4*)&a[0] = *(const float4*)&As[kk][ty * 8];
            *(float4*)&a[4] = *(const float4*)&As[kk][ty * 8 + 4];
            *(float4*)&b[0] = *(const float4*)&Bs[kk][tx * 8];
            *(float4*)&b[4] = *(const float4*)&Bs[kk][tx * 8 + 4];
            #pragma unroll
            for (int i = 0; i < 8; i++)
                #pragma unroll
                for (int j = 0; j < 8; j++)
                    acc[i][j] = fmaf(a[i], b[j], acc[i][j]);
        }
        __syncthreads();
    }

    // scatter epilogue: row m -> (b, s); col n -> (h, d); write (B,NH,S,D)
    #pragma unroll
    for (int i = 0; i < 8; i++) {
        const int m  = bm + ty * 8 + i;
        const int b_ = m >> 11;          // / 2048
        const int s  = m & (SEQ - 1);
        #pragma unroll
        for (int j = 0; j < 8; j++) {
            const int n = bn + tx * 8 + j;
            const int h = n >> 6, d = n & 63;
            out[(((size_t)(b_ * NH + h)) * SEQ + s) * HD + d] = acc[i][j] + bias[n];
        }
    }
}

// ---------------------------------------------------------------------------
// In-place RoPE on first 16 dims of each head of q and k.
// ---------------------------------------------------------------------------
__global__ __launch_bounds__(256)
void rope_kernel(float* __restrict__ q, float* __restrict__ k)
{
    const int idx = blockIdx.x * 256 + threadIdx.x;
    const int per = NB * NH * SEQ * 8;   // 524288
    float* x;
    int r;
    if (idx < per) { x = q; r = idx; } else { x = k; r = idx - per; }
    const int i  = r & 7;
    const int s  = (r >> 3) & (SEQ - 1);
    const int bh = r >> 14;              // 8*2048 = 2^14
    float* p = x + ((size_t)bh * SEQ + s) * HD;
    const float inv_freq = exp2f((float)i * (-13.287712379549449f / 8.0f));
    float sn, cs;
    sincosf((float)s * inv_freq, &sn, &cs);
    const float x1 = p[i], x2 = p[i + 8];
    p[i]     = fmaf(x1, cs, -x2 * sn);
    p[i + 8] = fmaf(x2, cs,  x1 * sn);
}

// ---------------------------------------------------------------------------
// Flash-style causal attention, restructured for VALU throughput:
//   - 4 lanes per q-row; lane owns a 16-dim quarter of q/acc.
//   - Per key: 16 FMAs (lane's quarter) + 2 shfl_xor to reduce the dot.
//   - Online softmax batched per 32-key chunk (scores held in 32 registers).
//   - PV: 16 independent-chain FMAs per key (no shuffles; p known to all 4
//     lanes after the reduce).
//   - K/V staged in LDS with row stride 68 words (64 would be 16-way bank
//     conflict; 68 -> 4-way on an undersubscribed pipe).
// Block = 256 threads = 64 q-rows. Grid = (S/64, NH, B) = 1024 blocks.
// ---------------------------------------------------------------------------
#define KCH 32
__global__ __launch_bounds__(256)
void attn_kernel(const float* __restrict__ qg, const float* __restrict__ kg,
                 const float* __restrict__ vg, float* __restrict__ out)
{
    __shared__ float Ks[KCH][68];
    __shared__ float Vs[KCH][68];

    const int tid = threadIdx.x;
    const int rl  = tid >> 2;          // local row 0..63
    const int dg  = tid & 3;           // d-quarter 0..3
    const int q0  = blockIdx.x * 64;
    const int h   = blockIdx.y;
    const int b   = blockIdx.z;
    const int r   = q0 + rl;           // this thread's q row
    const size_t base = ((size_t)(b * NH + h)) * SEQ * HD;

    // load q quarter, fold 1/sqrt(64)
    float q[16];
    #pragma unroll
    for (int t = 0; t < 4; t++) {
        float4 v = *(const float4*)&qg[base + (size_t)r * HD + dg * 16 + t * 4];
        q[t*4+0] = v.x * 0.125f; q[t*4+1] = v.y * 0.125f;
        q[t*4+2] = v.z * 0.125f; q[t*4+3] = v.w * 0.125f;
    }

    float acc[16] = {};
    float mrun = -3.0e38f, lrun = 0.f;

    const int jend = q0 + 64;          // keys needed by this block
    for (int j0 = 0; j0 < jend; j0 += KCH) {
        __syncthreads();
        // stage K,V chunk: 512 float4 per tensor, 2 per thread
        #pragma unroll
        for (int t = 0; t < 2; t++) {
            const int e  = tid + t * 256;       // 0..511
            const int j  = e >> 4;
            const int d4 = (e & 15) << 2;
            *(float4*)&Ks[j][d4] = *(const float4*)&kg[base + (size_t)(j0 + j) * HD + d4];
            *(float4*)&Vs[j][d4] = *(const float4*)&vg[base + (size_t)(j0 + j) * HD + d4];
        }
        __syncthreads();

        // scores for 32 keys
        float sc[KCH];
        #pragma unroll
        for (int jj = 0; jj < KCH; jj++) {
            float4 k0v = *(const float4*)&Ks[jj][dg * 16 + 0];
            float4 k1v = *(const float4*)&Ks[jj][dg * 16 + 4];
            float4 k2v = *(const float4*)&Ks[jj][dg * 16 + 8];
            float4 k3v = *(const float4*)&Ks[jj][dg * 16 + 12];
            float s0 = q[0]*k0v.x + q[1]*k0v.y + q[2]*k0v.z + q[3]*k0v.w;
            float s1 = q[4]*k1v.x + q[5]*k1v.y + q[6]*k1v.z + q[7]*k1v.w;
            float s2 = q[8]*k2v.x + q[9]*k2v.y + q[10]*k2v.z + q[11]*k2v.w;
            float s3 = q[12]*k3v.x + q[13]*k3v.y + q[14]*k3v.z + q[15]*k3v.w;
            float sv = (s0 + s1) + (s2 + s3);
            sv += __shfl_xor(sv, 1);
            sv += __shfl_xor(sv, 2);
            sc[jj] = (j0 + jj <= r) ? sv : -3.0e38f;
        }

        // online softmax update (all 4 lanes of a row hold identical sc[])
        float mx = sc[0];
        #pragma unroll
        for (int jj = 1; jj < KCH; jj++) mx = fmaxf(mx, sc[jj]);
        const float mn   = fmaxf(mrun, mx);
        const float corr = __expf(mrun - mn);
        float ps = 0.f;
        #pragma unroll
        for (int jj = 0; jj < KCH; jj++) { sc[jj] = __expf(sc[jj] - mn); ps += sc[jj]; }
        lrun = lrun * corr + ps;
        mrun = mn;
        #pragma unroll
        for (int i = 0; i < 16; i++) acc[i] *= corr;

        // PV: acc (lane's 16 dims) += p_j * V[j]
        #pragma unroll
        for (int jj = 0; jj < KCH; jj++) {
            const float p = sc[jj];
            float4 v0 = *(const float4*)&Vs[jj][dg * 16 + 0];
            float4 v1 = *(const float4*)&Vs[jj][dg * 16 + 4];
            float4 v2 = *(const float4*)&Vs[jj][dg * 16 + 8];
            float4 v3 = *(const float4*)&Vs[jj][dg * 16 + 12];
            acc[0]  = fmaf(p, v0.x, acc[0]);  acc[1]  = fmaf(p, v0.y, acc[1]);
            acc[2]  = fmaf(p, v0.z, acc[2]);  acc[3]  = fmaf(p, v0.w, acc[3]);
            acc[4]  = fmaf(p, v1.x, acc[4]);  acc[5]  = fmaf(p, v1.y, acc[5]);
            acc[6]  = fmaf(p, v1.z, acc[6]);  acc[7]  = fmaf(p, v1.w, acc[7]);
            acc[8]  = fmaf(p, v2.x, acc[8]);  acc[9]  = fmaf(p, v2.y, acc[9]);
            acc[10] = fmaf(p, v2.z, acc[10]); acc[11] = fmaf(p, v2.w, acc[11]);
            acc[12] = fmaf(p, v3.x, acc[12]); acc[13] = fmaf(p, v3.y, acc[13]);
            acc[14] = fmaf(p, v3.z, acc[14]); acc[15] = fmaf(p, v3.w, acc[15]);
        }
    }

    // finalize: out layout (B, S, NH*HD)
    const float inv = 1.0f / lrun;
    float* op = &out[(((size_t)(b * SEQ + r)) * NH + h) * HD + dg * 16];
    #pragma unroll
    for (int t = 0; t < 4; t++) {
        float4 o;
        o.x = acc[t*4+0] * inv; o.y = acc[t*4+1] * inv;
        o.z = acc[t*4+2] * inv; o.w = acc[t*4+3] * inv;
        *(float4*)&op[t*4] = o;
    }
}

// ---------------------------------------------------------------------------
// Output projection: attn (4096 x 1024) @ Wd (1024 x 1024) + bd -> d_out.
// ---------------------------------------------------------------------------
__global__ __launch_bounds__(256)
void proj_gemm(const float* __restrict__ A,
               const float* __restrict__ W, const float* __restrict__ bias,
               float* __restrict__ out)
{
    __shared__ float As[8][128];
    __shared__ float Bs[8][128];

    const int tid = threadIdx.x;
    const int bm = blockIdx.x * 128;
    const int bn = blockIdx.y * 128;
    const int tx = tid & 15;
    const int ty = tid >> 4;
    const int am  = tid >> 1;
    const int ak  = (tid & 1) * 4;
    const int bkr = tid >> 5;
    const int bn4 = (tid & 31) * 4;

    float acc[8][8] = {};

    for (int k0 = 0; k0 < HID; k0 += 8) {
        const float4 av  = *(const float4*)&A[(size_t)(bm + am) * HID + k0 + ak];
        const float4 bv4 = *(const float4*)&W[(size_t)(k0 + bkr) * HID + bn + bn4];
        As[ak + 0][am] = av.x; As[ak + 1][am] = av.y;
        As[ak + 2][am] = av.z; As[ak + 3][am] = av.w;
        *(float4*)&Bs[bkr][bn4] = bv4;
        __syncthreads();
        #pragma unroll
        for (int kk = 0; kk < 8; kk++) {
            float a[8], b[8];
            *(float4*)&a[0] = *(const float4*)&As[kk][ty * 8];
            *(float4*)&a[4] = *(const float4*)&As[kk][ty * 8 + 4];
            *(float4*)&b[0] = *(const float4*)&Bs[kk][tx * 8];
            *(float4*)&b[4] = *(const float4*)&Bs[kk][tx * 8 + 4];
            #pragma unroll
            for (int i = 0; i < 8; i++)
                #pragma unroll
                for (int j = 0; j < 8; j++)
                    acc[i][j] = fmaf(a[i], b[j], acc[i][j]);
        }
        __syncthreads();
    }

    #pragma unroll
    for (int i = 0; i < 8; i++) {
        const int m = bm + ty * 8 + i;
        #pragma unroll
        for (int j = 0; j < 8; j++) {
            const int n = bn + tx * 8 + j;
            out[(size_t)m * HID + n] = acc[i][j] + bias[n];
        }
    }
}

// ---------------------------------------------------------------------------
extern "C" void kernel_launch(void* const* d_in, const int* in_sizes, int n_in,
                              void* d_out, int out_size, void* d_ws, size_t ws_size,
                              hipStream_t stream)
{
    const float* ctx = (const float*)d_in[0];
    const float* Wq  = (const float*)d_in[1];
    const float* bq  = (const float*)d_in[2];
    const float* Wk  = (const float*)d_in[3];
    const float* bk  = (const float*)d_in[4];
    const float* Wv  = (const float*)d_in[5];
    const float* bv  = (const float*)d_in[6];
    const float* Wd  = (const float*)d_in[7];
    const float* bd  = (const float*)d_in[8];
    float* outp = (float*)d_out;

    // workspace: q, k, v in (B,NH,S,D) + attn in (B*S, HID); 64 MB fp32 total
    const size_t per = (size_t)NB * NH * SEQ * HD;  // 4,194,304 floats
    float* qw = (float*)d_ws;
    float* kw = qw + per;
    float* vw = kw + per;
    float* aw = vw + per;

    const dim3 blk(256);
    qkv_gemm <<<dim3(32, 8, 3),         blk, 0, stream>>>(ctx, Wq, bq, Wk, bk, Wv, bv, qw, kw, vw);
    rope_kernel<<<dim3(4096),           blk, 0, stream>>>(qw, kw);
    attn_kernel<<<dim3(SEQ/64, NH, NB), blk, 0, stream>>>(qw, kw, vw, aw);
    proj_gemm <<<dim3(32, 8),           blk, 0, stream>>>(aw, Wd, bd, outp);
}

// Round 7
// 547.469 us; speedup vs baseline: 4.8249x; 2.3519x over previous
//
#include <hip/hip_runtime.h>
#include <math.h>

#define NB   2
#define SEQ  2048
#define CDIM 512
#define HID  1024
#define NH   16
#define HD   64

typedef __attribute__((ext_vector_type(8))) short short8;
typedef __attribute__((ext_vector_type(4))) float f32x4;

__device__ __forceinline__ unsigned short f2b(float f) {
    union { float f; unsigned int u; } x; x.f = f;
    unsigned int r = x.u + 0x7fffu + ((x.u >> 16) & 1u);
    return (unsigned short)(r >> 16);
}
__device__ __forceinline__ float b2f(unsigned short s) {
    union { unsigned int u; float f; } x; x.u = ((unsigned int)s) << 16;
    return x.f;
}

// ---------------------------------------------------------------------------
// QKV projection (fp32 FMA GEMM, 128x128 tile). z=0: Q -> bf16 [b,h,s,d],
// scaled by 1/8. z=1: K -> bf16 [b,h,s,d]. z=2: V -> fp32 [b,h,s,d].
// ---------------------------------------------------------------------------
__global__ __launch_bounds__(256)
void qkv_gemm(const float* __restrict__ ctx,
              const float* __restrict__ Wq, const float* __restrict__ bq,
              const float* __restrict__ Wk, const float* __restrict__ bk,
              const float* __restrict__ Wv, const float* __restrict__ bv,
              unsigned short* __restrict__ qo, unsigned short* __restrict__ ko,
              float* __restrict__ vo)
{
    const int z = blockIdx.z;
    const float* __restrict__ W    = (z == 0) ? Wq : ((z == 1) ? Wk : Wv);
    const float* __restrict__ bias = (z == 0) ? bq : ((z == 1) ? bk : bv);

    __shared__ float As[8][128];
    __shared__ float Bs[8][128];

    const int tid = threadIdx.x;
    const int bm = blockIdx.x * 128;
    const int bn = blockIdx.y * 128;
    const int tx = tid & 15;
    const int ty = tid >> 4;
    const int am  = tid >> 1;
    const int ak  = (tid & 1) * 4;
    const int bkr = tid >> 5;
    const int bn4 = (tid & 31) * 4;

    float acc[8][8] = {};

    for (int k0 = 0; k0 < CDIM; k0 += 8) {
        const float4 av  = *(const float4*)&ctx[(size_t)(bm + am) * CDIM + k0 + ak];
        const float4 bv4 = *(const float4*)&W[(size_t)(k0 + bkr) * HID + bn + bn4];
        As[ak + 0][am] = av.x; As[ak + 1][am] = av.y;
        As[ak + 2][am] = av.z; As[ak + 3][am] = av.w;
        *(float4*)&Bs[bkr][bn4] = bv4;
        __syncthreads();
        #pragma unroll
        for (int kk = 0; kk < 8; kk++) {
            float a[8], b[8];
            *(float4*)&a[0] = *(const float4*)&As[kk][ty * 8];
            *(float4*)&a[4] = *(const float4*)&As[kk][ty * 8 + 4];
            *(float4*)&b[0] = *(const float4*)&Bs[kk][tx * 8];
            *(float4*)&b[4] = *(const float4*)&Bs[kk][tx * 8 + 4];
            #pragma unroll
            for (int i = 0; i < 8; i++)
                #pragma unroll
                for (int j = 0; j < 8; j++)
                    acc[i][j] = fmaf(a[i], b[j], acc[i][j]);
        }
        __syncthreads();
    }

    const int n0 = bn + tx * 8;          // 8 consecutive cols, same head
    const int hh = n0 >> 6;
    const int d0 = n0 & 63;
    if (z < 2) {
        unsigned short* __restrict__ outb = (z == 0) ? qo : ko;
        const float scl = (z == 0) ? 0.125f : 1.0f;
        #pragma unroll
        for (int i = 0; i < 8; i++) {
            const int m  = bm + ty * 8 + i;
            const int b_ = m >> 11;
            const int s  = m & (SEQ - 1);
            short8 t;
            #pragma unroll
            for (int j = 0; j < 8; j++)
                t[j] = (short)f2b((acc[i][j] + bias[n0 + j]) * scl);
            *(short8*)&outb[(((size_t)(b_ * NH + hh)) * SEQ + s) * HD + d0] = t;
        }
    } else {
        #pragma unroll
        for (int i = 0; i < 8; i++) {
            const int m  = bm + ty * 8 + i;
            const int b_ = m >> 11;
            const int s  = m & (SEQ - 1);
            #pragma unroll
            for (int j = 0; j < 8; j++)
                vo[(((size_t)(b_ * NH + hh)) * SEQ + s) * HD + d0 + j] = acc[i][j] + bias[n0 + j];
        }
    }
}

// ---------------------------------------------------------------------------
// In-place RoPE on bf16 q,k (first 16 dims of each head).
// ---------------------------------------------------------------------------
__global__ __launch_bounds__(256)
void rope_bf16(unsigned short* __restrict__ q, unsigned short* __restrict__ k)
{
    const int idx = blockIdx.x * 256 + threadIdx.x;
    const int per = NB * NH * SEQ * 8;   // 524288
    unsigned short* x;
    int r;
    if (idx < per) { x = q; r = idx; } else { x = k; r = idx - per; }
    const int i  = r & 7;
    const int s  = (r >> 3) & (SEQ - 1);
    const int bh = r >> 14;
    unsigned short* p = x + ((size_t)bh * SEQ + s) * HD;
    const float inv_freq = exp2f((float)i * (-13.287712379549449f / 8.0f));
    float sn, cs;
    sincosf((float)s * inv_freq, &sn, &cs);
    const float x1 = b2f(p[i]), x2 = b2f(p[i + 8]);
    p[i]     = f2b(fmaf(x1, cs, -x2 * sn));
    p[i + 8] = f2b(fmaf(x2, cs,  x1 * sn));
}

// ---------------------------------------------------------------------------
// V fp32 [bh][2048][64] -> bf16 transposed [bh][64][2048], LDS-tiled.
// ---------------------------------------------------------------------------
__global__ __launch_bounds__(256)
void pack_v(const float* __restrict__ v, unsigned short* __restrict__ vt)
{
    __shared__ unsigned short Lt[64][72];
    const int tid  = threadIdx.x;
    const int tile = blockIdx.x;
    const int bh   = blockIdx.y;
    const size_t ibase = ((size_t)bh * SEQ + tile * 64) * HD;
    #pragma unroll
    for (int it = 0; it < 4; it++) {
        const int ch  = tid + it * 256;
        const int row = ch >> 4;
        const int c4  = (ch & 15) * 4;
        const float4 a = *(const float4*)&v[ibase + (size_t)row * HD + c4];
        Lt[c4 + 0][row] = f2b(a.x);
        Lt[c4 + 1][row] = f2b(a.y);
        Lt[c4 + 2][row] = f2b(a.z);
        Lt[c4 + 3][row] = f2b(a.w);
    }
    __syncthreads();
    const size_t obase = (size_t)bh * HD * SEQ + tile * 64;
    #pragma unroll
    for (int it = 0; it < 4; it++) {
        const int ch = tid + it * 256;
        const int d  = ch >> 4;
        const int s4 = (ch & 15) * 4;
        ushort4 o;
        o.x = Lt[d][s4 + 0]; o.y = Lt[d][s4 + 1];
        o.z = Lt[d][s4 + 2]; o.w = Lt[d][s4 + 3];
        *(ushort4*)&vt[obase + (size_t)d * SEQ + s4] = o;
    }
}

// ---------------------------------------------------------------------------
// MFMA flash attention, causal. Block = 4 waves = 64 q-rows; K-blocks of 64.
// mfma_f32_16x16x32_bf16. C/D layout (HW-verified): col=lane&15,
// row=(lane>>4)*4+reg. A/B frags loaded with IDENTICAL per-lane k-indexing
// (self-consistent under any HW k-permutation since A/B layouts are
// symmetric). K/Vt/P LDS rows are 128B, XOR-swizzled: elem ^= (row&7)<<3
// so ds_read_b128 is conflict-free (Guideline 4 / T2).
// ---------------------------------------------------------------------------
__global__ __launch_bounds__(256)
void attn_mfma(const unsigned short* __restrict__ qg,
               const unsigned short* __restrict__ kg,
               const unsigned short* __restrict__ vtg,
               float* __restrict__ out)
{
    __shared__ unsigned short Ks[64 * 64];
    __shared__ unsigned short Vs[64 * 64];
    __shared__ unsigned short Ps[4][16 * 64];

    const int tid  = threadIdx.x;
    const int lane = tid & 63;
    const int wv   = tid >> 6;
    const int T    = (int)gridDim.x - 1 - (int)blockIdx.x;  // heavy tiles first
    const int h    = blockIdx.y, b = blockIdx.z;
    const int q0   = T * 64;
    const size_t base = ((size_t)(b * NH + h)) * SEQ * HD;

    const int lr = lane & 15;
    const int lk = lane >> 4;

    // Q A-frags (q pre-scaled by 1/8 upstream)
    const int qrow = q0 + wv * 16 + lr;
    const short8 qf0 = *(const short8*)&qg[base + (size_t)qrow * HD + lk * 8];
    const short8 qf1 = *(const short8*)&qg[base + (size_t)qrow * HD + 32 + lk * 8];

    f32x4 o[4] = {{0,0,0,0},{0,0,0,0},{0,0,0,0},{0,0,0,0}};
    float mrun[4], lrun[4];
    #pragma unroll
    for (int g = 0; g < 4; g++) { mrun[g] = -3.0e38f; lrun[g] = 0.f; }

    for (int kb = 0; kb <= T; kb++) {
        __syncthreads();
        // stage K[64][64] and Vt[64][64] (bf16), swizzled
        #pragma unroll
        for (int c = 0; c < 2; c++) {
            const int ch   = tid * 2 + c;      // 0..511
            const int row  = ch >> 3;
            const int slot = ch & 7;
            const int dst  = row * 64 + ((slot ^ (row & 7)) << 3);
            *(short8*)&Ks[dst] = *(const short8*)&kg[base + (size_t)(kb * 64 + row) * HD + slot * 8];
            *(short8*)&Vs[dst] = *(const short8*)&vtg[base + (size_t)row * SEQ + kb * 64 + slot * 8];
        }
        __syncthreads();

        // S = Q K^T : 4 key-tiles x 2 k-steps
        f32x4 s[4] = {{0,0,0,0},{0,0,0,0},{0,0,0,0},{0,0,0,0}};
        #pragma unroll
        for (int nt = 0; nt < 4; nt++) {
            const int krow = nt * 16 + lr;
            const int sw   = (krow & 7) << 3;
            const short8 kf0 = *(const short8*)&Ks[krow * 64 + ((lk * 8) ^ sw)];
            const short8 kf1 = *(const short8*)&Ks[krow * 64 + ((32 + lk * 8) ^ sw)];
            s[nt] = __builtin_amdgcn_mfma_f32_16x16x32_bf16(qf0, kf0, s[nt], 0, 0, 0);
            s[nt] = __builtin_amdgcn_mfma_f32_16x16x32_bf16(qf1, kf1, s[nt], 0, 0, 0);
        }

        // causal mask (only the diagonal 64x64 block)
        if (kb == T) {
            #pragma unroll
            for (int nt = 0; nt < 4; nt++)
                #pragma unroll
                for (int g = 0; g < 4; g++)
                    if (nt * 16 + lr > wv * 16 + lk * 4 + g) s[nt][g] = -3.0e38f;
        }

        // online softmax (rows live in 16-lane groups; reduce over lane&15)
        float corr[4], p[4][4];
        #pragma unroll
        for (int g = 0; g < 4; g++) {
            float mx = fmaxf(fmaxf(s[0][g], s[1][g]), fmaxf(s[2][g], s[3][g]));
            mx = fmaxf(mx, __shfl_xor(mx, 1));
            mx = fmaxf(mx, __shfl_xor(mx, 2));
            mx = fmaxf(mx, __shfl_xor(mx, 4));
            mx = fmaxf(mx, __shfl_xor(mx, 8));
            const float mn = fmaxf(mrun[g], mx);
            corr[g] = __expf(mrun[g] - mn);
            mrun[g] = mn;
            float rs = 0.f;
            #pragma unroll
            for (int nt = 0; nt < 4; nt++) { p[nt][g] = __expf(s[nt][g] - mn); rs += p[nt][g]; }
            rs += __shfl_xor(rs, 1);
            rs += __shfl_xor(rs, 2);
            rs += __shfl_xor(rs, 4);
            rs += __shfl_xor(rs, 8);
            lrun[g] = lrun[g] * corr[g] + rs;
        }
        #pragma unroll
        for (int dt = 0; dt < 4; dt++)
            #pragma unroll
            for (int g = 0; g < 4; g++)
                o[dt][g] *= corr[g];

        // P -> per-wave LDS (C-layout write), swizzled
        #pragma unroll
        for (int nt = 0; nt < 4; nt++)
            #pragma unroll
            for (int g = 0; g < 4; g++) {
                const int row = lk * 4 + g;
                const int col = nt * 16 + lr;
                Ps[wv][row * 64 + (col ^ ((row & 7) << 3))] = f2b(p[nt][g]);
            }
        __syncthreads();   // cross-lane P visibility

        // O += P V : A=P (rows=q), B=V (cols=d), same per-lane k-indexing
        const int psw = (lr & 7) << 3;
        #pragma unroll
        for (int ks = 0; ks < 2; ks++) {
            const short8 pf = *(const short8*)&Ps[wv][lr * 64 + ((ks * 32 + lk * 8) ^ psw)];
            #pragma unroll
            for (int dt = 0; dt < 4; dt++) {
                const int vrow = dt * 16 + lr;
                const short8 vf = *(const short8*)&Vs[vrow * 64 + ((ks * 32 + lk * 8) ^ psw)];
                o[dt] = __builtin_amdgcn_mfma_f32_16x16x32_bf16(pf, vf, o[dt], 0, 0, 0);
            }
        }
    }

    // epilogue: out (B, S, NH*HD) fp32
    #pragma unroll
    for (int g = 0; g < 4; g++) {
        const int qr = q0 + wv * 16 + lk * 4 + g;
        const float inv = 1.0f / lrun[g];
        float* op = &out[((size_t)(b * SEQ + qr)) * HID + h * HD + lr];
        op[0]  = o[0][g] * inv;
        op[16] = o[1][g] * inv;
        op[32] = o[2][g] * inv;
        op[48] = o[3][g] * inv;
    }
}

// ---------------------------------------------------------------------------
// Output projection: attn (4096 x 1024) @ Wd (1024 x 1024) + bd -> d_out.
// ---------------------------------------------------------------------------
__global__ __launch_bounds__(256)
void proj_gemm(const float* __restrict__ A,
               const float* __restrict__ W, const float* __restrict__ bias,
               float* __restrict__ out)
{
    __shared__ float As[8][128];
    __shared__ float Bs[8][128];

    const int tid = threadIdx.x;
    const int bm = blockIdx.x * 128;
    const int bn = blockIdx.y * 128;
    const int tx = tid & 15;
    const int ty = tid >> 4;
    const int am  = tid >> 1;
    const int ak  = (tid & 1) * 4;
    const int bkr = tid >> 5;
    const int bn4 = (tid & 31) * 4;

    float acc[8][8] = {};

    for (int k0 = 0; k0 < HID; k0 += 8) {
        const float4 av  = *(const float4*)&A[(size_t)(bm + am) * HID + k0 + ak];
        const float4 bv4 = *(const float4*)&W[(size_t)(k0 + bkr) * HID + bn + bn4];
        As[ak + 0][am] = av.x; As[ak + 1][am] = av.y;
        As[ak + 2][am] = av.z; As[ak + 3][am] = av.w;
        *(float4*)&Bs[bkr][bn4] = bv4;
        __syncthreads();
        #pragma unroll
        for (int kk = 0; kk < 8; kk++) {
            float a[8], b[8];
            *(float4*)&a[0] = *(const float4*)&As[kk][ty * 8];
            *(float4*)&a[4] = *(const float4*)&As[kk][ty * 8 + 4];
            *(float4*)&b[0] = *(const float4*)&Bs[kk][tx * 8];
            *(float4*)&b[4] = *(const float4*)&Bs[kk][tx * 8 + 4];
            #pragma unroll
            for (int i = 0; i < 8; i++)
                #pragma unroll
                for (int j = 0; j < 8; j++)
                    acc[i][j] = fmaf(a[i], b[j], acc[i][j]);
        }
        __syncthreads();
    }

    #pragma unroll
    for (int i = 0; i < 8; i++) {
        const int m = bm + ty * 8 + i;
        #pragma unroll
        for (int j = 0; j < 8; j++) {
            const int n = bn + tx * 8 + j;
            out[(size_t)m * HID + n] = acc[i][j] + bias[n];
        }
    }
}

// ---------------------------------------------------------------------------
extern "C" void kernel_launch(void* const* d_in, const int* in_sizes, int n_in,
                              void* d_out, int out_size, void* d_ws, size_t ws_size,
                              hipStream_t stream)
{
    const float* ctx = (const float*)d_in[0];
    const float* Wq  = (const float*)d_in[1];
    const float* bq  = (const float*)d_in[2];
    const float* Wk  = (const float*)d_in[3];
    const float* bk  = (const float*)d_in[4];
    const float* Wv  = (const float*)d_in[5];
    const float* bv  = (const float*)d_in[6];
    const float* Wd  = (const float*)d_in[7];
    const float* bd  = (const float*)d_in[8];
    float* outp = (float*)d_out;

    // workspace layout (56 MB total):
    //   [0,8MB)   qb  bf16 [b,h,s,d]
    //   [8,16MB)  kb  bf16 [b,h,s,d]
    //   [16,32MB) vw  fp32 [b,h,s,d]
    //   [32,40MB) vt  bf16 [b,h,d,s]
    //   [40,56MB) aw  fp32 [b,s,hid]
    const size_t per = (size_t)NB * NH * SEQ * HD;   // 4,194,304
    unsigned short* qb = (unsigned short*)d_ws;
    unsigned short* kb = qb + per;
    float*          vw = (float*)((char*)d_ws + (size_t)16 * 1024 * 1024);
    unsigned short* vt = (unsigned short*)((char*)d_ws + (size_t)32 * 1024 * 1024);
    float*          aw = (float*)((char*)d_ws + (size_t)40 * 1024 * 1024);

    const dim3 blk(256);
    qkv_gemm <<<dim3(32, 8, 3),  blk, 0, stream>>>(ctx, Wq, bq, Wk, bk, Wv, bv, qb, kb, vw);
    rope_bf16<<<dim3(4096),      blk, 0, stream>>>(qb, kb);
    pack_v   <<<dim3(32, 32),    blk, 0, stream>>>(vw, vt);
    attn_mfma<<<dim3(32, NH, NB), blk, 0, stream>>>(qb, kb, vt, aw);
    proj_gemm<<<dim3(32, 8),     blk, 0, stream>>>(aw, Wd, bd, outp);
}

// Round 8
// 266.572 us; speedup vs baseline: 9.9091x; 2.0537x over previous
//
#include <hip/hip_runtime.h>
#include <math.h>

#define NB   2
#define SEQ  2048
#define CDIM 512
#define HID  1024
#define NH   16
#define HD   64

typedef __attribute__((ext_vector_type(8))) short short8;
typedef __attribute__((ext_vector_type(4))) float f32x4;

__device__ __forceinline__ unsigned short f2b(float f) {
    union { float f; unsigned int u; } x; x.f = f;
    unsigned int r = x.u + 0x7fffu + ((x.u >> 16) & 1u);
    return (unsigned short)(r >> 16);
}
__device__ __forceinline__ float b2f(unsigned short s) {
    union { unsigned int u; float f; } x; x.u = ((unsigned int)s) << 16;
    return x.f;
}

// ---------------------------------------------------------------------------
// ctx fp32 -> bf16 straight convert (float4 -> ushort4 per thread).
// ---------------------------------------------------------------------------
__global__ __launch_bounds__(256)
void pack_ctx(const float* __restrict__ src, unsigned short* __restrict__ dst)
{
    const int idx = blockIdx.x * 256 + threadIdx.x;   // one float4
    const float4 a = *(const float4*)&src[(size_t)idx * 4];
    ushort4 o;
    o.x = f2b(a.x); o.y = f2b(a.y); o.z = f2b(a.z); o.w = f2b(a.w);
    *(ushort4*)&dst[(size_t)idx * 4] = o;
}

// ---------------------------------------------------------------------------
// Weight transpose+convert: src fp32 [K x N] -> dst bf16 [N x K].
// blockIdx.z selects among 3 (src,dst) pairs (pass same ptr for 1-array use).
// ---------------------------------------------------------------------------
__global__ __launch_bounds__(256)
void packT(const float* __restrict__ s0, const float* __restrict__ s1,
           const float* __restrict__ s2,
           unsigned short* __restrict__ d0, unsigned short* __restrict__ d1,
           unsigned short* __restrict__ d2, int K, int N)
{
    const int z = blockIdx.z;
    const float* __restrict__ src = (z == 0) ? s0 : ((z == 1) ? s1 : s2);
    unsigned short* __restrict__ dst = (z == 0) ? d0 : ((z == 1) ? d1 : d2);

    __shared__ unsigned short Lt[64][72];
    const int tid = threadIdx.x;
    const int k0 = blockIdx.x * 64;
    const int n0 = blockIdx.y * 64;
    #pragma unroll
    for (int it = 0; it < 4; it++) {
        const int ch  = tid + it * 256;
        const int row = ch >> 4;            // k within tile
        const int c4  = (ch & 15) * 4;      // n within tile
        const float4 a = *(const float4*)&src[(size_t)(k0 + row) * N + n0 + c4];
        Lt[c4 + 0][row] = f2b(a.x);
        Lt[c4 + 1][row] = f2b(a.y);
        Lt[c4 + 2][row] = f2b(a.z);
        Lt[c4 + 3][row] = f2b(a.w);
    }
    __syncthreads();
    #pragma unroll
    for (int it = 0; it < 4; it++) {
        const int ch = tid + it * 256;
        const int d  = ch >> 4;             // n within tile
        const int k4 = (ch & 15) * 4;       // k within tile
        ushort4 o;
        o.x = Lt[d][k4 + 0]; o.y = Lt[d][k4 + 1];
        o.z = Lt[d][k4 + 2]; o.w = Lt[d][k4 + 3];
        *(ushort4*)&dst[(size_t)(n0 + d) * K + k0 + k4] = o;
    }
}

// ---------------------------------------------------------------------------
// QKV projection, bf16 MFMA. C = ctxb[4096x512] @ W[512x1024] (+bias).
// Tile 128x64 (BN=64 = exactly one head), BK=64, 4 waves (2x2), each wave
// 64x32 = 4x2 fragments of 16x16. A and Bt both k-contiguous; LDS rows are
// 128B XOR-swizzled (elem ^= (row&7)<<3) -- same verified structure as
// attn_mfma. z selects Q (scale 1/8) / K / V, all emitted bf16 scattered
// to [b,h,s,d].
// ---------------------------------------------------------------------------
__global__ __launch_bounds__(256)
void qkv_mfma(const unsigned short* __restrict__ Ab,
              const unsigned short* __restrict__ wqt,
              const unsigned short* __restrict__ wkt,
              const unsigned short* __restrict__ wvt,
              const float* __restrict__ bq, const float* __restrict__ bk,
              const float* __restrict__ bv,
              unsigned short* __restrict__ qo, unsigned short* __restrict__ ko,
              unsigned short* __restrict__ vo)
{
    const int z = blockIdx.z;
    const unsigned short* __restrict__ Bt = (z == 0) ? wqt : ((z == 1) ? wkt : wvt);
    const float* __restrict__ bias        = (z == 0) ? bq  : ((z == 1) ? bk  : bv);
    unsigned short* __restrict__ out      = (z == 0) ? qo  : ((z == 1) ? ko  : vo);
    const float scl = (z == 0) ? 0.125f : 1.0f;

    __shared__ unsigned short As[128 * 64];
    __shared__ unsigned short Bs[64 * 64];

    const int tid  = threadIdx.x;
    const int lane = tid & 63;
    const int wid  = tid >> 6;
    const int wr   = wid >> 1, wc = wid & 1;
    const int lr   = lane & 15, lk = lane >> 4;
    const int bm   = blockIdx.x * 128;
    const int h    = blockIdx.y;

    const f32x4 z4 = {0.f, 0.f, 0.f, 0.f};
    f32x4 acc[4][2];
    #pragma unroll
    for (int m = 0; m < 4; m++) { acc[m][0] = z4; acc[m][1] = z4; }

    for (int kt = 0; kt < CDIM / 64; kt++) {
        __syncthreads();
        #pragma unroll
        for (int it = 0; it < 4; it++) {
            const int ch = tid + it * 256;
            const int row = ch >> 3, slot = ch & 7;
            *(short8*)&As[row * 64 + ((slot ^ (row & 7)) << 3)] =
                *(const short8*)&Ab[(size_t)(bm + row) * CDIM + kt * 64 + slot * 8];
        }
        #pragma unroll
        for (int it = 0; it < 2; it++) {
            const int ch = tid + it * 256;
            const int row = ch >> 3, slot = ch & 7;
            *(short8*)&Bs[row * 64 + ((slot ^ (row & 7)) << 3)] =
                *(const short8*)&Bt[(size_t)(h * 64 + row) * CDIM + kt * 64 + slot * 8];
        }
        __syncthreads();
        const int sw = (lr & 7) << 3;
        #pragma unroll
        for (int ks = 0; ks < 2; ks++) {
            short8 bfr[2], afr[4];
            #pragma unroll
            for (int n = 0; n < 2; n++)
                bfr[n] = *(const short8*)&Bs[(wc * 32 + n * 16 + lr) * 64 + ((ks * 32 + lk * 8) ^ sw)];
            #pragma unroll
            for (int m = 0; m < 4; m++)
                afr[m] = *(const short8*)&As[(wr * 64 + m * 16 + lr) * 64 + ((ks * 32 + lk * 8) ^ sw)];
            #pragma unroll
            for (int m = 0; m < 4; m++)
                #pragma unroll
                for (int n = 0; n < 2; n++)
                    acc[m][n] = __builtin_amdgcn_mfma_f32_16x16x32_bf16(afr[m], bfr[n], acc[m][n], 0, 0, 0);
        }
    }

    // epilogue: scatter bf16 to [b,h,s,d]
    #pragma unroll
    for (int m = 0; m < 4; m++) {
        #pragma unroll
        for (int g = 0; g < 4; g++) {
            const int mrow = bm + wr * 64 + m * 16 + lk * 4 + g;
            const int b_ = mrow >> 11;
            const int s  = mrow & (SEQ - 1);
            #pragma unroll
            for (int n = 0; n < 2; n++) {
                const int d = wc * 32 + n * 16 + lr;
                out[(((size_t)(b_ * NH + h)) * SEQ + s) * HD + d] =
                    f2b((acc[m][n][g] + bias[h * 64 + d]) * scl);
            }
        }
    }
}

// ---------------------------------------------------------------------------
// In-place RoPE on bf16 q,k (first 16 dims of each head).
// ---------------------------------------------------------------------------
__global__ __launch_bounds__(256)
void rope_bf16(unsigned short* __restrict__ q, unsigned short* __restrict__ k)
{
    const int idx = blockIdx.x * 256 + threadIdx.x;
    const int per = NB * NH * SEQ * 8;   // 524288
    unsigned short* x;
    int r;
    if (idx < per) { x = q; r = idx; } else { x = k; r = idx - per; }
    const int i  = r & 7;
    const int s  = (r >> 3) & (SEQ - 1);
    const int bh = r >> 14;
    unsigned short* p = x + ((size_t)bh * SEQ + s) * HD;
    const float inv_freq = exp2f((float)i * (-13.287712379549449f / 8.0f));
    float sn, cs;
    sincosf((float)s * inv_freq, &sn, &cs);
    const float x1 = b2f(p[i]), x2 = b2f(p[i + 8]);
    p[i]     = f2b(fmaf(x1, cs, -x2 * sn));
    p[i + 8] = f2b(fmaf(x2, cs,  x1 * sn));
}

// ---------------------------------------------------------------------------
// V bf16 [bh][2048][64] -> bf16 transposed [bh][64][2048], LDS-tiled.
// ---------------------------------------------------------------------------
__global__ __launch_bounds__(256)
void pack_v(const unsigned short* __restrict__ v, unsigned short* __restrict__ vt)
{
    __shared__ unsigned short Lt[64][72];
    const int tid  = threadIdx.x;
    const int tile = blockIdx.x;
    const int bh   = blockIdx.y;
    const size_t ibase = ((size_t)bh * SEQ + tile * 64) * HD;
    #pragma unroll
    for (int it = 0; it < 4; it++) {
        const int ch  = tid + it * 256;
        const int row = ch >> 4;            // s within tile
        const int c4  = (ch & 15) * 4;      // d
        const ushort4 a = *(const ushort4*)&v[ibase + (size_t)row * HD + c4];
        Lt[c4 + 0][row] = a.x;
        Lt[c4 + 1][row] = a.y;
        Lt[c4 + 2][row] = a.z;
        Lt[c4 + 3][row] = a.w;
    }
    __syncthreads();
    const size_t obase = (size_t)bh * HD * SEQ + tile * 64;
    #pragma unroll
    for (int it = 0; it < 4; it++) {
        const int ch = tid + it * 256;
        const int d  = ch >> 4;
        const int s4 = (ch & 15) * 4;
        ushort4 o;
        o.x = Lt[d][s4 + 0]; o.y = Lt[d][s4 + 1];
        o.z = Lt[d][s4 + 2]; o.w = Lt[d][s4 + 3];
        *(ushort4*)&vt[obase + (size_t)d * SEQ + s4] = o;
    }
}

// ---------------------------------------------------------------------------
// MFMA flash attention, causal (structure validated in Round 7 bench).
// Output now bf16 (feeds proj's MFMA A-operand directly).
// ---------------------------------------------------------------------------
__global__ __launch_bounds__(256)
void attn_mfma(const unsigned short* __restrict__ qg,
               const unsigned short* __restrict__ kg,
               const unsigned short* __restrict__ vtg,
               unsigned short* __restrict__ out)
{
    __shared__ unsigned short Ks[64 * 64];
    __shared__ unsigned short Vs[64 * 64];
    __shared__ unsigned short Ps[4][16 * 64];

    const int tid  = threadIdx.x;
    const int lane = tid & 63;
    const int wv   = tid >> 6;
    const int T    = (int)gridDim.x - 1 - (int)blockIdx.x;  // heavy tiles first
    const int h    = blockIdx.y, b = blockIdx.z;
    const int q0   = T * 64;
    const size_t base = ((size_t)(b * NH + h)) * SEQ * HD;

    const int lr = lane & 15;
    const int lk = lane >> 4;

    const int qrow = q0 + wv * 16 + lr;
    const short8 qf0 = *(const short8*)&qg[base + (size_t)qrow * HD + lk * 8];
    const short8 qf1 = *(const short8*)&qg[base + (size_t)qrow * HD + 32 + lk * 8];

    const f32x4 z4 = {0.f, 0.f, 0.f, 0.f};
    f32x4 o[4] = {z4, z4, z4, z4};
    float mrun[4], lrun[4];
    #pragma unroll
    for (int g = 0; g < 4; g++) { mrun[g] = -3.0e38f; lrun[g] = 0.f; }

    for (int kb = 0; kb <= T; kb++) {
        __syncthreads();
        #pragma unroll
        for (int c = 0; c < 2; c++) {
            const int ch   = tid * 2 + c;
            const int row  = ch >> 3;
            const int slot = ch & 7;
            const int dst  = row * 64 + ((slot ^ (row & 7)) << 3);
            *(short8*)&Ks[dst] = *(const short8*)&kg[base + (size_t)(kb * 64 + row) * HD + slot * 8];
            *(short8*)&Vs[dst] = *(const short8*)&vtg[base + (size_t)row * SEQ + kb * 64 + slot * 8];
        }
        __syncthreads();

        f32x4 s[4] = {z4, z4, z4, z4};
        #pragma unroll
        for (int nt = 0; nt < 4; nt++) {
            const int krow = nt * 16 + lr;
            const int sw   = (krow & 7) << 3;
            const short8 kf0 = *(const short8*)&Ks[krow * 64 + ((lk * 8) ^ sw)];
            const short8 kf1 = *(const short8*)&Ks[krow * 64 + ((32 + lk * 8) ^ sw)];
            s[nt] = __builtin_amdgcn_mfma_f32_16x16x32_bf16(qf0, kf0, s[nt], 0, 0, 0);
            s[nt] = __builtin_amdgcn_mfma_f32_16x16x32_bf16(qf1, kf1, s[nt], 0, 0, 0);
        }

        if (kb == T) {
            #pragma unroll
            for (int nt = 0; nt < 4; nt++)
                #pragma unroll
                for (int g = 0; g < 4; g++)
                    if (nt * 16 + lr > wv * 16 + lk * 4 + g) s[nt][g] = -3.0e38f;
        }

        float corr[4], p[4][4];
        #pragma unroll
        for (int g = 0; g < 4; g++) {
            float mx = fmaxf(fmaxf(s[0][g], s[1][g]), fmaxf(s[2][g], s[3][g]));
            mx = fmaxf(mx, __shfl_xor(mx, 1));
            mx = fmaxf(mx, __shfl_xor(mx, 2));
            mx = fmaxf(mx, __shfl_xor(mx, 4));
            mx = fmaxf(mx, __shfl_xor(mx, 8));
            const float mn = fmaxf(mrun[g], mx);
            corr[g] = __expf(mrun[g] - mn);
            mrun[g] = mn;
            float rs = 0.f;
            #pragma unroll
            for (int nt = 0; nt < 4; nt++) { p[nt][g] = __expf(s[nt][g] - mn); rs += p[nt][g]; }
            rs += __shfl_xor(rs, 1);
            rs += __shfl_xor(rs, 2);
            rs += __shfl_xor(rs, 4);
            rs += __shfl_xor(rs, 8);
            lrun[g] = lrun[g] * corr[g] + rs;
        }
        #pragma unroll
        for (int dt = 0; dt < 4; dt++)
            #pragma unroll
            for (int g = 0; g < 4; g++)
                o[dt][g] *= corr[g];

        #pragma unroll
        for (int nt = 0; nt < 4; nt++)
            #pragma unroll
            for (int g = 0; g < 4; g++) {
                const int row = lk * 4 + g;
                const int col = nt * 16 + lr;
                Ps[wv][row * 64 + (col ^ ((row & 7) << 3))] = f2b(p[nt][g]);
            }
        __syncthreads();

        const int psw = (lr & 7) << 3;
        #pragma unroll
        for (int ks = 0; ks < 2; ks++) {
            const short8 pf = *(const short8*)&Ps[wv][lr * 64 + ((ks * 32 + lk * 8) ^ psw)];
            #pragma unroll
            for (int dt = 0; dt < 4; dt++) {
                const int vrow = dt * 16 + lr;
                const short8 vf = *(const short8*)&Vs[vrow * 64 + ((ks * 32 + lk * 8) ^ psw)];
                o[dt] = __builtin_amdgcn_mfma_f32_16x16x32_bf16(pf, vf, o[dt], 0, 0, 0);
            }
        }
    }

    // epilogue: bf16 out (B, S, NH*HD)
    #pragma unroll
    for (int g = 0; g < 4; g++) {
        const int qr = q0 + wv * 16 + lk * 4 + g;
        const float inv = 1.0f / lrun[g];
        unsigned short* op = &out[((size_t)(b * SEQ + qr)) * HID + h * HD + lr];
        op[0]  = f2b(o[0][g] * inv);
        op[16] = f2b(o[1][g] * inv);
        op[32] = f2b(o[2][g] * inv);
        op[48] = f2b(o[3][g] * inv);
    }
}

// ---------------------------------------------------------------------------
// Output projection, bf16 MFMA: aw[4096x1024] @ Wd + bd -> d_out fp32.
// Same core as qkv_mfma; tile 128x64, BK=64.
// ---------------------------------------------------------------------------
__global__ __launch_bounds__(256)
void proj_mfma(const unsigned short* __restrict__ Ab,
               const unsigned short* __restrict__ Bt,
               const float* __restrict__ bias, float* __restrict__ out)
{
    __shared__ unsigned short As[128 * 64];
    __shared__ unsigned short Bs[64 * 64];

    const int tid  = threadIdx.x;
    const int lane = tid & 63;
    const int wid  = tid >> 6;
    const int wr   = wid >> 1, wc = wid & 1;
    const int lr   = lane & 15, lk = lane >> 4;
    const int bm   = blockIdx.x * 128;
    const int bn   = blockIdx.y * 64;

    const f32x4 z4 = {0.f, 0.f, 0.f, 0.f};
    f32x4 acc[4][2];
    #pragma unroll
    for (int m = 0; m < 4; m++) { acc[m][0] = z4; acc[m][1] = z4; }

    for (int kt = 0; kt < HID / 64; kt++) {
        __syncthreads();
        #pragma unroll
        for (int it = 0; it < 4; it++) {
            const int ch = tid + it * 256;
            const int row = ch >> 3, slot = ch & 7;
            *(short8*)&As[row * 64 + ((slot ^ (row & 7)) << 3)] =
                *(const short8*)&Ab[(size_t)(bm + row) * HID + kt * 64 + slot * 8];
        }
        #pragma unroll
        for (int it = 0; it < 2; it++) {
            const int ch = tid + it * 256;
            const int row = ch >> 3, slot = ch & 7;
            *(short8*)&Bs[row * 64 + ((slot ^ (row & 7)) << 3)] =
                *(const short8*)&Bt[(size_t)(bn + row) * HID + kt * 64 + slot * 8];
        }
        __syncthreads();
        const int sw = (lr & 7) << 3;
        #pragma unroll
        for (int ks = 0; ks < 2; ks++) {
            short8 bfr[2], afr[4];
            #pragma unroll
            for (int n = 0; n < 2; n++)
                bfr[n] = *(const short8*)&Bs[(wc * 32 + n * 16 + lr) * 64 + ((ks * 32 + lk * 8) ^ sw)];
            #pragma unroll
            for (int m = 0; m < 4; m++)
                afr[m] = *(const short8*)&As[(wr * 64 + m * 16 + lr) * 64 + ((ks * 32 + lk * 8) ^ sw)];
            #pragma unroll
            for (int m = 0; m < 4; m++)
                #pragma unroll
                for (int n = 0; n < 2; n++)
                    acc[m][n] = __builtin_amdgcn_mfma_f32_16x16x32_bf16(afr[m], bfr[n], acc[m][n], 0, 0, 0);
        }
    }

    #pragma unroll
    for (int m = 0; m < 4; m++) {
        #pragma unroll
        for (int g = 0; g < 4; g++) {
            const int mrow = bm + wr * 64 + m * 16 + lk * 4 + g;
            #pragma unroll
            for (int n = 0; n < 2; n++) {
                const int ncol = bn + wc * 32 + n * 16 + lr;
                out[(size_t)mrow * HID + ncol] = acc[m][n][g] + bias[ncol];
            }
        }
    }
}

// ---------------------------------------------------------------------------
extern "C" void kernel_launch(void* const* d_in, const int* in_sizes, int n_in,
                              void* d_out, int out_size, void* d_ws, size_t ws_size,
                              hipStream_t stream)
{
    const float* ctx = (const float*)d_in[0];
    const float* Wq  = (const float*)d_in[1];
    const float* bq  = (const float*)d_in[2];
    const float* Wk  = (const float*)d_in[3];
    const float* bk  = (const float*)d_in[4];
    const float* Wv  = (const float*)d_in[5];
    const float* bv  = (const float*)d_in[6];
    const float* Wd  = (const float*)d_in[7];
    const float* bd  = (const float*)d_in[8];
    float* outp = (float*)d_out;

    // workspace layout (49 MB total), all bf16 unless noted:
    //   [0,4MB)    ctxb [4096x512]
    //   [4,5MB)    wqt  [1024x512]   (transposed)
    //   [5,6MB)    wkt  [1024x512]
    //   [6,7MB)    wvt  [1024x512]
    //   [7,9MB)    wdt  [1024x1024]  (transposed)
    //   [9,17MB)   qb   [b,h,s,d]
    //   [17,25MB)  kb   [b,h,s,d]
    //   [25,33MB)  vb   [b,h,s,d]
    //   [33,41MB)  vt   [b,h,d,s]
    //   [41,49MB)  aw   [4096x1024]  (attention output)
    char* w = (char*)d_ws;
    unsigned short* ctxb = (unsigned short*)(w);
    unsigned short* wqt  = (unsigned short*)(w + (size_t)4  * 1024 * 1024);
    unsigned short* wkt  = (unsigned short*)(w + (size_t)5  * 1024 * 1024);
    unsigned short* wvt  = (unsigned short*)(w + (size_t)6  * 1024 * 1024);
    unsigned short* wdt  = (unsigned short*)(w + (size_t)7  * 1024 * 1024);
    unsigned short* qb   = (unsigned short*)(w + (size_t)9  * 1024 * 1024);
    unsigned short* kb   = (unsigned short*)(w + (size_t)17 * 1024 * 1024);
    unsigned short* vb   = (unsigned short*)(w + (size_t)25 * 1024 * 1024);
    unsigned short* vt   = (unsigned short*)(w + (size_t)33 * 1024 * 1024);
    unsigned short* aw   = (unsigned short*)(w + (size_t)41 * 1024 * 1024);

    const dim3 blk(256);
    pack_ctx <<<dim3(2048),        blk, 0, stream>>>(ctx, ctxb);                 // 2M elems / 4 / 256
    packT    <<<dim3(8, 16, 3),    blk, 0, stream>>>(Wq, Wk, Wv, wqt, wkt, wvt, CDIM, HID);
    packT    <<<dim3(16, 16, 1),   blk, 0, stream>>>(Wd, Wd, Wd, wdt, wdt, wdt, HID, HID);
    qkv_mfma <<<dim3(32, 16, 3),   blk, 0, stream>>>(ctxb, wqt, wkt, wvt, bq, bk, bv, qb, kb, vb);
    rope_bf16<<<dim3(4096),        blk, 0, stream>>>(qb, kb);
    pack_v   <<<dim3(32, 32),      blk, 0, stream>>>(vb, vt);
    attn_mfma<<<dim3(32, NH, NB),  blk, 0, stream>>>(qb, kb, vt, aw);
    proj_mfma<<<dim3(32, 16),      blk, 0, stream>>>(aw, wdt, bd, outp);
}

// Round 11
// 182.767 us; speedup vs baseline: 14.4527x; 1.4585x over previous
//
#include <hip/hip_runtime.h>
#include <math.h>

#define NB   2
#define SEQ  2048
#define CDIM 512
#define HID  1024
#define NH   16
#define HD   64

typedef __attribute__((ext_vector_type(8))) short short8;
typedef __attribute__((ext_vector_type(4))) float f32x4;

__device__ __forceinline__ unsigned short f2b(float f) {
    union { float f; unsigned int u; } x; x.f = f;
    unsigned int r = x.u + 0x7fffu + ((x.u >> 16) & 1u);
    return (unsigned short)(r >> 16);
}
__device__ __forceinline__ float b2f(unsigned short s) {
    union { unsigned int u; float f; } x; x.u = ((unsigned int)s) << 16;
    return x.f;
}

// ---------------------------------------------------------------------------
// ctx fp32 -> bf16 straight convert.
// ---------------------------------------------------------------------------
__global__ __launch_bounds__(256)
void pack_ctx(const float* __restrict__ src, unsigned short* __restrict__ dst)
{
    const int idx = blockIdx.x * 256 + threadIdx.x;
    const float4 a = *(const float4*)&src[(size_t)idx * 4];
    ushort4 o;
    o.x = f2b(a.x); o.y = f2b(a.y); o.z = f2b(a.z); o.w = f2b(a.w);
    *(ushort4*)&dst[(size_t)idx * 4] = o;
}

// ---------------------------------------------------------------------------
// Weight transpose+convert: src fp32 [K x N] -> dst bf16 [N x K].
// ---------------------------------------------------------------------------
__global__ __launch_bounds__(256)
void packT(const float* __restrict__ s0, const float* __restrict__ s1,
           const float* __restrict__ s2,
           unsigned short* __restrict__ d0, unsigned short* __restrict__ d1,
           unsigned short* __restrict__ d2, int K, int N)
{
    const int z = blockIdx.z;
    const float* __restrict__ src = (z == 0) ? s0 : ((z == 1) ? s1 : s2);
    unsigned short* __restrict__ dst = (z == 0) ? d0 : ((z == 1) ? d1 : d2);

    __shared__ unsigned short Lt[64][72];
    const int tid = threadIdx.x;
    const int k0 = blockIdx.x * 64;
    const int n0 = blockIdx.y * 64;
    #pragma unroll
    for (int it = 0; it < 4; it++) {
        const int ch  = tid + it * 256;
        const int row = ch >> 4;
        const int c4  = (ch & 15) * 4;
        const float4 a = *(const float4*)&src[(size_t)(k0 + row) * N + n0 + c4];
        Lt[c4 + 0][row] = f2b(a.x);
        Lt[c4 + 1][row] = f2b(a.y);
        Lt[c4 + 2][row] = f2b(a.z);
        Lt[c4 + 3][row] = f2b(a.w);
    }
    __syncthreads();
    #pragma unroll
    for (int it = 0; it < 4; it++) {
        const int ch = tid + it * 256;
        const int d  = ch >> 4;
        const int k4 = (ch & 15) * 4;
        ushort4 o;
        o.x = Lt[d][k4 + 0]; o.y = Lt[d][k4 + 1];
        o.z = Lt[d][k4 + 2]; o.w = Lt[d][k4 + 3];
        *(ushort4*)&dst[(size_t)(n0 + d) * K + k0 + k4] = o;
    }
}

// ---------------------------------------------------------------------------
// QKV projection, bf16 MFMA (validated Round 8). z: Q(×1/8)/K/V -> bf16 [b,h,s,d].
// ---------------------------------------------------------------------------
__global__ __launch_bounds__(256)
void qkv_mfma(const unsigned short* __restrict__ Ab,
              const unsigned short* __restrict__ wqt,
              const unsigned short* __restrict__ wkt,
              const unsigned short* __restrict__ wvt,
              const float* __restrict__ bq, const float* __restrict__ bk,
              const float* __restrict__ bv,
              unsigned short* __restrict__ qo, unsigned short* __restrict__ ko,
              unsigned short* __restrict__ vo)
{
    const int z = blockIdx.z;
    const unsigned short* __restrict__ Bt = (z == 0) ? wqt : ((z == 1) ? wkt : wvt);
    const float* __restrict__ bias        = (z == 0) ? bq  : ((z == 1) ? bk  : bv);
    unsigned short* __restrict__ out      = (z == 0) ? qo  : ((z == 1) ? ko  : vo);
    const float scl = (z == 0) ? 0.125f : 1.0f;

    __shared__ unsigned short As[128 * 64];
    __shared__ unsigned short Bs[64 * 64];

    const int tid  = threadIdx.x;
    const int lane = tid & 63;
    const int wid  = tid >> 6;
    const int wr   = wid >> 1, wc = wid & 1;
    const int lr   = lane & 15, lk = lane >> 4;
    const int bm   = blockIdx.x * 128;
    const int h    = blockIdx.y;

    const f32x4 z4 = {0.f, 0.f, 0.f, 0.f};
    f32x4 acc[4][2];
    #pragma unroll
    for (int m = 0; m < 4; m++) { acc[m][0] = z4; acc[m][1] = z4; }

    for (int kt = 0; kt < CDIM / 64; kt++) {
        __syncthreads();
        #pragma unroll
        for (int it = 0; it < 4; it++) {
            const int ch = tid + it * 256;
            const int row = ch >> 3, slot = ch & 7;
            *(short8*)&As[row * 64 + ((slot ^ (row & 7)) << 3)] =
                *(const short8*)&Ab[(size_t)(bm + row) * CDIM + kt * 64 + slot * 8];
        }
        #pragma unroll
        for (int it = 0; it < 2; it++) {
            const int ch = tid + it * 256;
            const int row = ch >> 3, slot = ch & 7;
            *(short8*)&Bs[row * 64 + ((slot ^ (row & 7)) << 3)] =
                *(const short8*)&Bt[(size_t)(h * 64 + row) * CDIM + kt * 64 + slot * 8];
        }
        __syncthreads();
        const int sw = (lr & 7) << 3;
        #pragma unroll
        for (int ks = 0; ks < 2; ks++) {
            short8 bfr[2], afr[4];
            #pragma unroll
            for (int n = 0; n < 2; n++)
                bfr[n] = *(const short8*)&Bs[(wc * 32 + n * 16 + lr) * 64 + ((ks * 32 + lk * 8) ^ sw)];
            #pragma unroll
            for (int m = 0; m < 4; m++)
                afr[m] = *(const short8*)&As[(wr * 64 + m * 16 + lr) * 64 + ((ks * 32 + lk * 8) ^ sw)];
            #pragma unroll
            for (int m = 0; m < 4; m++)
                #pragma unroll
                for (int n = 0; n < 2; n++)
                    acc[m][n] = __builtin_amdgcn_mfma_f32_16x16x32_bf16(afr[m], bfr[n], acc[m][n], 0, 0, 0);
        }
    }

    #pragma unroll
    for (int m = 0; m < 4; m++) {
        #pragma unroll
        for (int g = 0; g < 4; g++) {
            const int mrow = bm + wr * 64 + m * 16 + lk * 4 + g;
            const int b_ = mrow >> 11;
            const int s  = mrow & (SEQ - 1);
            #pragma unroll
            for (int n = 0; n < 2; n++) {
                const int d = wc * 32 + n * 16 + lr;
                out[(((size_t)(b_ * NH + h)) * SEQ + s) * HD + d] =
                    f2b((acc[m][n][g] + bias[h * 64 + d]) * scl);
            }
        }
    }
}

// ---------------------------------------------------------------------------
// In-place RoPE on bf16 q,k (first 16 dims of each head).
// ---------------------------------------------------------------------------
__global__ __launch_bounds__(256)
void rope_bf16(unsigned short* __restrict__ q, unsigned short* __restrict__ k)
{
    const int idx = blockIdx.x * 256 + threadIdx.x;
    const int per = NB * NH * SEQ * 8;
    unsigned short* x;
    int r;
    if (idx < per) { x = q; r = idx; } else { x = k; r = idx - per; }
    const int i  = r & 7;
    const int s  = (r >> 3) & (SEQ - 1);
    const int bh = r >> 14;
    unsigned short* p = x + ((size_t)bh * SEQ + s) * HD;
    const float inv_freq = exp2f((float)i * (-13.287712379549449f / 8.0f));
    float sn, cs;
    sincosf((float)s * inv_freq, &sn, &cs);
    const float x1 = b2f(p[i]), x2 = b2f(p[i + 8]);
    p[i]     = f2b(fmaf(x1, cs, -x2 * sn));
    p[i + 8] = f2b(fmaf(x2, cs,  x1 * sn));
}

// ---------------------------------------------------------------------------
// V bf16 [bh][2048][64] -> bf16 transposed [bh][64][2048].
// ---------------------------------------------------------------------------
__global__ __launch_bounds__(256)
void pack_v(const unsigned short* __restrict__ v, unsigned short* __restrict__ vt)
{
    __shared__ unsigned short Lt[64][72];
    const int tid  = threadIdx.x;
    const int tile = blockIdx.x;
    const int bh   = blockIdx.y;
    const size_t ibase = ((size_t)bh * SEQ + tile * 64) * HD;
    #pragma unroll
    for (int it = 0; it < 4; it++) {
        const int ch  = tid + it * 256;
        const int row = ch >> 4;
        const int c4  = (ch & 15) * 4;
        const ushort4 a = *(const ushort4*)&v[ibase + (size_t)row * HD + c4];
        Lt[c4 + 0][row] = a.x;
        Lt[c4 + 1][row] = a.y;
        Lt[c4 + 2][row] = a.z;
        Lt[c4 + 3][row] = a.w;
    }
    __syncthreads();
    const size_t obase = (size_t)bh * HD * SEQ + tile * 64;
    #pragma unroll
    for (int it = 0; it < 4; it++) {
        const int ch = tid + it * 256;
        const int d  = ch >> 4;
        const int s4 = (ch & 15) * 4;
        ushort4 o;
        o.x = Lt[d][s4 + 0]; o.y = Lt[d][s4 + 1];
        o.z = Lt[d][s4 + 2]; o.w = Lt[d][s4 + 3];
        *(ushort4*)&vt[obase + (size_t)d * SEQ + s4] = o;
    }
}

// ---------------------------------------------------------------------------
// MFMA flash attention v2, causal.
//  - Triangular pairing: block p does tiles {p, 31-p} -> uniform 33 iters.
//  - Swapped QK^T (mfma(K,Q) -> S^T): lane holds 16 scores of ONE q-row
//    (q = lane&15); row-reduce = in-reg + shfl_xor(16,32) only.
//  - P written back as P[q][key] (packed u32, XOR swizzle keyed on q-row),
//    read as PV A-fragment exactly like the validated round-8 pattern.
//  - P barrier -> wave-local s_waitcnt (P is per-wave LDS).
//  - K/V register prefetch: next tile's global loads issued right after
//    ds_writes, hide under compute (T14).
// ---------------------------------------------------------------------------
__global__ __launch_bounds__(256)
void attn_mfma(const unsigned short* __restrict__ qg,
               const unsigned short* __restrict__ kg,
               const unsigned short* __restrict__ vtg,
               unsigned short* __restrict__ out)
{
    __shared__ unsigned short Ks[64 * 64];
    __shared__ unsigned short Vs[64 * 64];
    __shared__ unsigned short Ps[4][16 * 64];

    const int tid  = threadIdx.x;
    const int lane = tid & 63;
    const int wv   = tid >> 6;
    const int p    = blockIdx.x;           // 0..15
    const int h    = blockIdx.y, b = blockIdx.z;
    const size_t base = ((size_t)(b * NH + h)) * SEQ * HD;

    const int lr = lane & 15;
    const int lk = lane >> 4;

    // staging geometry (2 chunks per thread)
    const int ch0 = tid * 2, ch1 = tid * 2 + 1;
    const int r0 = ch0 >> 3, sl0 = ch0 & 7;
    const int r1 = ch1 >> 3, sl1 = ch1 & 7;
    const int dd0 = r0 * 64 + ((sl0 ^ (r0 & 7)) << 3);
    const int dd1 = r1 * 64 + ((sl1 ^ (r1 & 7)) << 3);

    const f32x4 z4 = {0.f, 0.f, 0.f, 0.f};

    #pragma unroll
    for (int half = 0; half < 2; half++) {
        const int T  = half ? (31 - p) : p;
        const int q0 = T * 64;

        // Q as B-operand: lane holds col=q=lr, k-slice lk*8..+7 (pre-scaled 1/8)
        const int qrow = q0 + wv * 16 + lr;
        const short8 qf0 = *(const short8*)&qg[base + (size_t)qrow * HD + lk * 8];
        const short8 qf1 = *(const short8*)&qg[base + (size_t)qrow * HD + 32 + lk * 8];

        f32x4 o[4] = {z4, z4, z4, z4};
        float mrun = -3.0e38f, lrun = 0.f;   // state for q-row lr

        // prologue prefetch kb=0
        short8 kp0 = *(const short8*)&kg[base + (size_t)r0 * HD + sl0 * 8];
        short8 kp1 = *(const short8*)&kg[base + (size_t)r1 * HD + sl1 * 8];
        short8 vp0 = *(const short8*)&vtg[base + (size_t)r0 * SEQ + sl0 * 8];
        short8 vp1 = *(const short8*)&vtg[base + (size_t)r1 * SEQ + sl1 * 8];

        for (int kb = 0; kb <= T; kb++) {
            __syncthreads();                       // prev LDS reads done
            *(short8*)&Ks[dd0] = kp0;
            *(short8*)&Ks[dd1] = kp1;
            *(short8*)&Vs[dd0] = vp0;
            *(short8*)&Vs[dd1] = vp1;
            if (kb < T) {                          // prefetch next tile
                const int kn = kb + 1;
                kp0 = *(const short8*)&kg[base + (size_t)(kn * 64 + r0) * HD + sl0 * 8];
                kp1 = *(const short8*)&kg[base + (size_t)(kn * 64 + r1) * HD + sl1 * 8];
                vp0 = *(const short8*)&vtg[base + (size_t)r0 * SEQ + kn * 64 + sl0 * 8];
                vp1 = *(const short8*)&vtg[base + (size_t)r1 * SEQ + kn * 64 + sl1 * 8];
            }
            __syncthreads();                       // LDS ready

            // S^T = K Q^T : A=K (row=key), B=Q (col=q)
            f32x4 s[4] = {z4, z4, z4, z4};
            #pragma unroll
            for (int nt = 0; nt < 4; nt++) {
                const int krow = nt * 16 + lr;
                const int sw   = (krow & 7) << 3;
                const short8 kf0 = *(const short8*)&Ks[krow * 64 + ((lk * 8) ^ sw)];
                const short8 kf1 = *(const short8*)&Ks[krow * 64 + ((32 + lk * 8) ^ sw)];
                s[nt] = __builtin_amdgcn_mfma_f32_16x16x32_bf16(kf0, qf0, s[nt], 0, 0, 0);
                s[nt] = __builtin_amdgcn_mfma_f32_16x16x32_bf16(kf1, qf1, s[nt], 0, 0, 0);
            }
            // s[nt][g] = score(key = nt*16 + lk*4 + g, q = lr)

            if (kb == T) {   // diagonal causal mask: key > q
                #pragma unroll
                for (int nt = 0; nt < 4; nt++)
                    #pragma unroll
                    for (int g = 0; g < 4; g++)
                        if (nt * 16 + lk * 4 + g > wv * 16 + lr) s[nt][g] = -3.0e38f;
            }

            // softmax for q-row lr: in-reg max/sum + xor(16,32) across lk groups
            float mx = -3.0e38f;
            #pragma unroll
            for (int nt = 0; nt < 4; nt++)
                #pragma unroll
                for (int g = 0; g < 4; g++) mx = fmaxf(mx, s[nt][g]);
            mx = fmaxf(mx, __shfl_xor(mx, 16));
            mx = fmaxf(mx, __shfl_xor(mx, 32));
            const float mn   = fmaxf(mrun, mx);
            const float corr = __expf(mrun - mn);
            mrun = mn;
            float pp[4][4];
            float rs = 0.f;
            #pragma unroll
            for (int nt = 0; nt < 4; nt++)
                #pragma unroll
                for (int g = 0; g < 4; g++) { pp[nt][g] = __expf(s[nt][g] - mn); rs += pp[nt][g]; }
            rs += __shfl_xor(rs, 16);
            rs += __shfl_xor(rs, 32);
            lrun = lrun * corr + rs;

            // rescale O: o[dt][g] belongs to q=lk*4+g -> broadcast corr
            #pragma unroll
            for (int g = 0; g < 4; g++) {
                const float cg = __shfl(corr, lk * 4 + g);
                #pragma unroll
                for (int dt = 0; dt < 4; dt++) o[dt][g] *= cg;
            }

            // P[q=lr][key] packed u32 writes, swizzle keyed on row lr
            const int psw = (lr & 7) << 3;
            #pragma unroll
            for (int nt = 0; nt < 4; nt++) {
                const int c0 = (nt * 16 + lk * 4) ^ psw;
                const unsigned int w01 = (unsigned int)f2b(pp[nt][0]) | ((unsigned int)f2b(pp[nt][1]) << 16);
                const unsigned int w23 = (unsigned int)f2b(pp[nt][2]) | ((unsigned int)f2b(pp[nt][3]) << 16);
                *(unsigned int*)&Ps[wv][lr * 64 + c0]     = w01;
                *(unsigned int*)&Ps[wv][lr * 64 + c0 + 2] = w23;
            }
            // P is per-wave LDS: wave-local fence, no block barrier
            asm volatile("s_waitcnt lgkmcnt(0)" ::: "memory");

            // O += P V : A=P (row=q), B=V^T (col=d)
            #pragma unroll
            for (int ks = 0; ks < 2; ks++) {
                const short8 pf = *(const short8*)&Ps[wv][lr * 64 + ((ks * 32 + lk * 8) ^ psw)];
                #pragma unroll
                for (int dt = 0; dt < 4; dt++) {
                    const int vrow = dt * 16 + lr;
                    const short8 vf = *(const short8*)&Vs[vrow * 64 + ((ks * 32 + lk * 8) ^ psw)];
                    o[dt] = __builtin_amdgcn_mfma_f32_16x16x32_bf16(pf, vf, o[dt], 0, 0, 0);
                }
            }
        }

        // epilogue: bf16 out (B, S, NH*HD); lrun lives at lane lk*4+g
        #pragma unroll
        for (int g = 0; g < 4; g++) {
            const int qr = q0 + wv * 16 + lk * 4 + g;
            const float lg  = __shfl(lrun, lk * 4 + g);
            const float inv = 1.0f / lg;
            unsigned short* op = &out[((size_t)(b * SEQ + qr)) * HID + h * HD + lr];
            op[0]  = f2b(o[0][g] * inv);
            op[16] = f2b(o[1][g] * inv);
            op[32] = f2b(o[2][g] * inv);
            op[48] = f2b(o[3][g] * inv);
        }
    }
}

// ---------------------------------------------------------------------------
// Output projection, bf16 MFMA (validated Round 8).
// ---------------------------------------------------------------------------
__global__ __launch_bounds__(256)
void proj_mfma(const unsigned short* __restrict__ Ab,
               const unsigned short* __restrict__ Bt,
               const float* __restrict__ bias, float* __restrict__ out)
{
    __shared__ unsigned short As[128 * 64];
    __shared__ unsigned short Bs[64 * 64];

    const int tid  = threadIdx.x;
    const int lane = tid & 63;
    const int wid  = tid >> 6;
    const int wr   = wid >> 1, wc = wid & 1;
    const int lr   = lane & 15, lk = lane >> 4;
    const int bm   = blockIdx.x * 128;
    const int bn   = blockIdx.y * 64;

    const f32x4 z4 = {0.f, 0.f, 0.f, 0.f};
    f32x4 acc[4][2];
    #pragma unroll
    for (int m = 0; m < 4; m++) { acc[m][0] = z4; acc[m][1] = z4; }

    for (int kt = 0; kt < HID / 64; kt++) {
        __syncthreads();
        #pragma unroll
        for (int it = 0; it < 4; it++) {
            const int ch = tid + it * 256;
            const int row = ch >> 3, slot = ch & 7;
            *(short8*)&As[row * 64 + ((slot ^ (row & 7)) << 3)] =
                *(const short8*)&Ab[(size_t)(bm + row) * HID + kt * 64 + slot * 8];
        }
        #pragma unroll
        for (int it = 0; it < 2; it++) {
            const int ch = tid + it * 256;
            const int row = ch >> 3, slot = ch & 7;
            *(short8*)&Bs[row * 64 + ((slot ^ (row & 7)) << 3)] =
                *(const short8*)&Bt[(size_t)(bn + row) * HID + kt * 64 + slot * 8];
        }
        __syncthreads();
        const int sw = (lr & 7) << 3;
        #pragma unroll
        for (int ks = 0; ks < 2; ks++) {
            short8 bfr[2], afr[4];
            #pragma unroll
            for (int n = 0; n < 2; n++)
                bfr[n] = *(const short8*)&Bs[(wc * 32 + n * 16 + lr) * 64 + ((ks * 32 + lk * 8) ^ sw)];
            #pragma unroll
            for (int m = 0; m < 4; m++)
                afr[m] = *(const short8*)&As[(wr * 64 + m * 16 + lr) * 64 + ((ks * 32 + lk * 8) ^ sw)];
            #pragma unroll
            for (int m = 0; m < 4; m++)
                #pragma unroll
                for (int n = 0; n < 2; n++)
                    acc[m][n] = __builtin_amdgcn_mfma_f32_16x16x32_bf16(afr[m], bfr[n], acc[m][n], 0, 0, 0);
        }
    }

    #pragma unroll
    for (int m = 0; m < 4; m++) {
        #pragma unroll
        for (int g = 0; g < 4; g++) {
            const int mrow = bm + wr * 64 + m * 16 + lk * 4 + g;
            #pragma unroll
            for (int n = 0; n < 2; n++) {
                const int ncol = bn + wc * 32 + n * 16 + lr;
                out[(size_t)mrow * HID + ncol] = acc[m][n][g] + bias[ncol];
            }
        }
    }
}

// ---------------------------------------------------------------------------
extern "C" void kernel_launch(void* const* d_in, const int* in_sizes, int n_in,
                              void* d_out, int out_size, void* d_ws, size_t ws_size,
                              hipStream_t stream)
{
    const float* ctx = (const float*)d_in[0];
    const float* Wq  = (const float*)d_in[1];
    const float* bq  = (const float*)d_in[2];
    const float* Wk  = (const float*)d_in[3];
    const float* bk  = (const float*)d_in[4];
    const float* Wv  = (const float*)d_in[5];
    const float* bv  = (const float*)d_in[6];
    const float* Wd  = (const float*)d_in[7];
    const float* bd  = (const float*)d_in[8];
    float* outp = (float*)d_out;

    char* w = (char*)d_ws;
    unsigned short* ctxb = (unsigned short*)(w);
    unsigned short* wqt  = (unsigned short*)(w + (size_t)4  * 1024 * 1024);
    unsigned short* wkt  = (unsigned short*)(w + (size_t)5  * 1024 * 1024);
    unsigned short* wvt  = (unsigned short*)(w + (size_t)6  * 1024 * 1024);
    unsigned short* wdt  = (unsigned short*)(w + (size_t)7  * 1024 * 1024);
    unsigned short* qb   = (unsigned short*)(w + (size_t)9  * 1024 * 1024);
    unsigned short* kb   = (unsigned short*)(w + (size_t)17 * 1024 * 1024);
    unsigned short* vb   = (unsigned short*)(w + (size_t)25 * 1024 * 1024);
    unsigned short* vt   = (unsigned short*)(w + (size_t)33 * 1024 * 1024);
    unsigned short* aw   = (unsigned short*)(w + (size_t)41 * 1024 * 1024);

    const dim3 blk(256);
    pack_ctx <<<dim3(2048),        blk, 0, stream>>>(ctx, ctxb);
    packT    <<<dim3(8, 16, 3),    blk, 0, stream>>>(Wq, Wk, Wv, wqt, wkt, wvt, CDIM, HID);
    packT    <<<dim3(16, 16, 1),   blk, 0, stream>>>(Wd, Wd, Wd, wdt, wdt, wdt, HID, HID);
    qkv_mfma <<<dim3(32, 16, 3),   blk, 0, stream>>>(ctxb, wqt, wkt, wvt, bq, bk, bv, qb, kb, vb);
    rope_bf16<<<dim3(4096),        blk, 0, stream>>>(qb, kb);
    pack_v   <<<dim3(32, 32),      blk, 0, stream>>>(vb, vt);
    attn_mfma<<<dim3(16, NH, NB),  blk, 0, stream>>>(qb, kb, vt, aw);
    proj_mfma<<<dim3(32, 16),      blk, 0, stream>>>(aw, wdt, bd, outp);
}

// Round 13
// 171.466 us; speedup vs baseline: 15.4053x; 1.0659x over previous
//
#include <hip/hip_runtime.h>
#include <math.h>

#define NB   2
#define SEQ  2048
#define CDIM 512
#define HID  1024
#define NH   16
#define HD   64

typedef __attribute__((ext_vector_type(8))) short short8;
typedef __attribute__((ext_vector_type(4))) float f32x4;

__device__ __forceinline__ unsigned short f2b(float f) {
    union { float f; unsigned int u; } x; x.f = f;
    unsigned int r = x.u + 0x7fffu + ((x.u >> 16) & 1u);
    return (unsigned short)(r >> 16);
}
// native bf16 pair-pack (compiler emits v_cvt_pk_bf16_f32; m240: don't hand-asm)
__device__ __forceinline__ unsigned int pk2(float a, float b) {
    __bf16 x = (__bf16)a, y = (__bf16)b;
    unsigned short ux = __builtin_bit_cast(unsigned short, x);
    unsigned short uy = __builtin_bit_cast(unsigned short, y);
    return (unsigned int)ux | ((unsigned int)uy << 16);
}
__device__ __forceinline__ float b2f(unsigned short s) {
    union { unsigned int u; float f; } x; x.u = ((unsigned int)s) << 16;
    return x.f;
}
// bare v_exp_f32 (2^x) — scores are kept in log2 domain
__device__ __forceinline__ float fexp2(float x) {
    float r;
    asm("v_exp_f32 %0, %1" : "=v"(r) : "v"(x));
    return r;
}

// ---------------------------------------------------------------------------
// pack4: one launch for all input packing. grid (16,16,5).
//   z in {0,1,2}: Wq/Wk/Wv fp32[512x1024] -> bf16 [1024x512] (transposed)
//   z == 3     : Wd fp32[1024x1024] -> bf16 [1024x1024] (transposed)
//   z == 4     : ctx fp32[4096x512] -> bf16 (straight convert)
// ---------------------------------------------------------------------------
__global__ __launch_bounds__(256)
void pack4(const float* __restrict__ Wq, const float* __restrict__ Wk,
           const float* __restrict__ Wv, const float* __restrict__ Wd,
           const float* __restrict__ ctx,
           unsigned short* __restrict__ wqt, unsigned short* __restrict__ wkt,
           unsigned short* __restrict__ wvt, unsigned short* __restrict__ wdt,
           unsigned short* __restrict__ ctxb)
{
    const int z   = blockIdx.z;
    const int tid = threadIdx.x;

    if (z == 4) {   // ctx convert: 256 blocks x 2048 float4
        const int blk = blockIdx.y * 16 + blockIdx.x;
        #pragma unroll
        for (int it = 0; it < 8; it++) {
            const int idx = blk * 2048 + it * 256 + tid;
            const float4 a = *(const float4*)&ctx[(size_t)idx * 4];
            ushort4 o;
            o.x = f2b(a.x); o.y = f2b(a.y); o.z = f2b(a.z); o.w = f2b(a.w);
            *(ushort4*)&ctxb[(size_t)idx * 4] = o;
        }
        return;
    }

    const int K = (z == 3) ? HID : CDIM;
    const int k0 = blockIdx.x * 64;
    if (k0 >= K) return;
    const int n0 = blockIdx.y * 64;
    const float* __restrict__ src = (z == 0) ? Wq : ((z == 1) ? Wk : ((z == 2) ? Wv : Wd));
    unsigned short* __restrict__ dst = (z == 0) ? wqt : ((z == 1) ? wkt : ((z == 2) ? wvt : wdt));

    __shared__ unsigned short Lt[64][72];
    #pragma unroll
    for (int it = 0; it < 4; it++) {
        const int ch  = tid + it * 256;
        const int row = ch >> 4;
        const int c4  = (ch & 15) * 4;
        const float4 a = *(const float4*)&src[(size_t)(k0 + row) * HID + n0 + c4];
        Lt[c4 + 0][row] = f2b(a.x);
        Lt[c4 + 1][row] = f2b(a.y);
        Lt[c4 + 2][row] = f2b(a.z);
        Lt[c4 + 3][row] = f2b(a.w);
    }
    __syncthreads();
    #pragma unroll
    for (int it = 0; it < 4; it++) {
        const int ch = tid + it * 256;
        const int d  = ch >> 4;
        const int k4 = (ch & 15) * 4;
        ushort4 o;
        o.x = Lt[d][k4 + 0]; o.y = Lt[d][k4 + 1];
        o.z = Lt[d][k4 + 2]; o.w = Lt[d][k4 + 3];
        *(ushort4*)&dst[(size_t)(n0 + d) * K + k0 + k4] = o;
    }
}

// ---------------------------------------------------------------------------
// QKV projection, bf16 MFMA. z=0: Q scaled by 0.125*log2(e) -> [b,h,s,d];
// z=1: K -> [b,h,s,d]; z=2: V written TRANSPOSED to vt[b,h,d,s] directly
// (4 g-values are s-consecutive -> ushort4 stores). pack_v kernel deleted.
// ---------------------------------------------------------------------------
__global__ __launch_bounds__(256)
void qkv_mfma(const unsigned short* __restrict__ Ab,
              const unsigned short* __restrict__ wqt,
              const unsigned short* __restrict__ wkt,
              const unsigned short* __restrict__ wvt,
              const float* __restrict__ bq, const float* __restrict__ bk,
              const float* __restrict__ bv,
              unsigned short* __restrict__ qo, unsigned short* __restrict__ ko,
              unsigned short* __restrict__ vt)
{
    const int z = blockIdx.z;
    const unsigned short* __restrict__ Bt = (z == 0) ? wqt : ((z == 1) ? wkt : wvt);
    const float* __restrict__ bias        = (z == 0) ? bq  : ((z == 1) ? bk  : bv);
    const float scl = (z == 0) ? 0.125f * 1.44269504f : 1.0f;  // log2e folded into Q

    __shared__ unsigned short As[128 * 64];
    __shared__ unsigned short Bs[64 * 64];

    const int tid  = threadIdx.x;
    const int lane = tid & 63;
    const int wid  = tid >> 6;
    const int wr   = wid >> 1, wc = wid & 1;
    const int lr   = lane & 15, lk = lane >> 4;
    const int bm   = blockIdx.x * 128;
    const int h    = blockIdx.y;

    const f32x4 z4 = {0.f, 0.f, 0.f, 0.f};
    f32x4 acc[4][2];
    #pragma unroll
    for (int m = 0; m < 4; m++) { acc[m][0] = z4; acc[m][1] = z4; }

    for (int kt = 0; kt < CDIM / 64; kt++) {
        __syncthreads();
        #pragma unroll
        for (int it = 0; it < 4; it++) {
            const int ch = tid + it * 256;
            const int row = ch >> 3, slot = ch & 7;
            *(short8*)&As[row * 64 + ((slot ^ (row & 7)) << 3)] =
                *(const short8*)&Ab[(size_t)(bm + row) * CDIM + kt * 64 + slot * 8];
        }
        #pragma unroll
        for (int it = 0; it < 2; it++) {
            const int ch = tid + it * 256;
            const int row = ch >> 3, slot = ch & 7;
            *(short8*)&Bs[row * 64 + ((slot ^ (row & 7)) << 3)] =
                *(const short8*)&Bt[(size_t)(h * 64 + row) * CDIM + kt * 64 + slot * 8];
        }
        __syncthreads();
        const int sw = (lr & 7) << 3;
        #pragma unroll
        for (int ks = 0; ks < 2; ks++) {
            short8 bfr[2], afr[4];
            #pragma unroll
            for (int n = 0; n < 2; n++)
                bfr[n] = *(const short8*)&Bs[(wc * 32 + n * 16 + lr) * 64 + ((ks * 32 + lk * 8) ^ sw)];
            #pragma unroll
            for (int m = 0; m < 4; m++)
                afr[m] = *(const short8*)&As[(wr * 64 + m * 16 + lr) * 64 + ((ks * 32 + lk * 8) ^ sw)];
            #pragma unroll
            for (int m = 0; m < 4; m++)
                #pragma unroll
                for (int n = 0; n < 2; n++)
                    acc[m][n] = __builtin_amdgcn_mfma_f32_16x16x32_bf16(afr[m], bfr[n], acc[m][n], 0, 0, 0);
        }
    }

    if (z < 2) {
        unsigned short* __restrict__ out = (z == 0) ? qo : ko;
        #pragma unroll
        for (int m = 0; m < 4; m++) {
            #pragma unroll
            for (int g = 0; g < 4; g++) {
                const int mrow = bm + wr * 64 + m * 16 + lk * 4 + g;
                const int b_ = mrow >> 11;
                const int s  = mrow & (SEQ - 1);
                #pragma unroll
                for (int n = 0; n < 2; n++) {
                    const int d = wc * 32 + n * 16 + lr;
                    out[(((size_t)(b_ * NH + h)) * SEQ + s) * HD + d] =
                        f2b((acc[m][n][g] + bias[h * 64 + d]) * scl);
                }
            }
        }
    } else {
        // V: write transposed vt[b,h,d,s]; g-values are s-consecutive
        #pragma unroll
        for (int m = 0; m < 4; m++) {
            const int mrow0 = bm + wr * 64 + m * 16 + lk * 4;
            const int b_ = mrow0 >> 11;
            const int s0 = mrow0 & (SEQ - 1);
            #pragma unroll
            for (int n = 0; n < 2; n++) {
                const int d = wc * 32 + n * 16 + lr;
                const float bs = bias[h * 64 + d];
                ushort4 o4;
                o4.x = f2b(acc[m][n][0] + bs);
                o4.y = f2b(acc[m][n][1] + bs);
                o4.z = f2b(acc[m][n][2] + bs);
                o4.w = f2b(acc[m][n][3] + bs);
                *(ushort4*)&vt[(((size_t)(b_ * NH + h)) * HD + d) * SEQ + s0] = o4;
            }
        }
    }
}

// ---------------------------------------------------------------------------
// In-place RoPE on bf16 q,k (first 16 dims of each head). Linear op, commutes
// with Q's constant pre-scale.
// ---------------------------------------------------------------------------
__global__ __launch_bounds__(256)
void rope_bf16(unsigned short* __restrict__ q, unsigned short* __restrict__ k)
{
    const int idx = blockIdx.x * 256 + threadIdx.x;
    const int per = NB * NH * SEQ * 8;
    unsigned short* x;
    int r;
    if (idx < per) { x = q; r = idx; } else { x = k; r = idx - per; }
    const int i  = r & 7;
    const int s  = (r >> 3) & (SEQ - 1);
    const int bh = r >> 14;
    unsigned short* p = x + ((size_t)bh * SEQ + s) * HD;
    const float inv_freq = exp2f((float)i * (-13.287712379549449f / 8.0f));
    float sn, cs;
    sincosf((float)s * inv_freq, &sn, &cs);
    const float x1 = b2f(p[i]), x2 = b2f(p[i + 8]);
    p[i]     = f2b(fmaf(x1, cs, -x2 * sn));
    p[i + 8] = f2b(fmaf(x2, cs,  x1 * sn));
}

// ---------------------------------------------------------------------------
// MFMA flash attention v3, causal. v2 structure (triangular pairing, swapped
// QK^T, wave-local P fence, K/V reg prefetch) + this round:
//  - log2-domain softmax: p = 2^(s-m) via bare v_exp_f32 (log2e pre-folded
//    into Q upstream).
//  - defer-max (T13): skip O-rescale + max update while __any(mx>mrun+11)
//    is false (2^11 bound is bf16-safe; exact in fp32 otherwise).
//  - P-pack via native __bf16 casts (compiler emits cvt_pk).
// ---------------------------------------------------------------------------
__global__ __launch_bounds__(256)
void attn_mfma(const unsigned short* __restrict__ qg,
               const unsigned short* __restrict__ kg,
               const unsigned short* __restrict__ vtg,
               unsigned short* __restrict__ out)
{
    __shared__ unsigned short Ks[64 * 64];
    __shared__ unsigned short Vs[64 * 64];
    __shared__ unsigned short Ps[4][16 * 64];

    const int tid  = threadIdx.x;
    const int lane = tid & 63;
    const int wv   = tid >> 6;
    const int p    = blockIdx.x;           // 0..15
    const int h    = blockIdx.y, b = blockIdx.z;
    const size_t base = ((size_t)(b * NH + h)) * SEQ * HD;

    const int lr = lane & 15;
    const int lk = lane >> 4;

    const int ch0 = tid * 2, ch1 = tid * 2 + 1;
    const int r0 = ch0 >> 3, sl0 = ch0 & 7;
    const int r1 = ch1 >> 3, sl1 = ch1 & 7;
    const int dd0 = r0 * 64 + ((sl0 ^ (r0 & 7)) << 3);
    const int dd1 = r1 * 64 + ((sl1 ^ (r1 & 7)) << 3);

    const f32x4 z4 = {0.f, 0.f, 0.f, 0.f};

    #pragma unroll
    for (int half = 0; half < 2; half++) {
        const int T  = half ? (31 - p) : p;
        const int q0 = T * 64;

        const int qrow = q0 + wv * 16 + lr;
        const short8 qf0 = *(const short8*)&qg[base + (size_t)qrow * HD + lk * 8];
        const short8 qf1 = *(const short8*)&qg[base + (size_t)qrow * HD + 32 + lk * 8];

        f32x4 o[4] = {z4, z4, z4, z4};
        float mrun = -3.0e38f, lrun = 0.f;

        short8 kp0 = *(const short8*)&kg[base + (size_t)r0 * HD + sl0 * 8];
        short8 kp1 = *(const short8*)&kg[base + (size_t)r1 * HD + sl1 * 8];
        short8 vp0 = *(const short8*)&vtg[base + (size_t)r0 * SEQ + sl0 * 8];
        short8 vp1 = *(const short8*)&vtg[base + (size_t)r1 * SEQ + sl1 * 8];

        for (int kb = 0; kb <= T; kb++) {
            __syncthreads();
            *(short8*)&Ks[dd0] = kp0;
            *(short8*)&Ks[dd1] = kp1;
            *(short8*)&Vs[dd0] = vp0;
            *(short8*)&Vs[dd1] = vp1;
            if (kb < T) {
                const int kn = kb + 1;
                kp0 = *(const short8*)&kg[base + (size_t)(kn * 64 + r0) * HD + sl0 * 8];
                kp1 = *(const short8*)&kg[base + (size_t)(kn * 64 + r1) * HD + sl1 * 8];
                vp0 = *(const short8*)&vtg[base + (size_t)r0 * SEQ + kn * 64 + sl0 * 8];
                vp1 = *(const short8*)&vtg[base + (size_t)r1 * SEQ + kn * 64 + sl1 * 8];
            }
            __syncthreads();

            // S^T = K Q^T (log2-domain scores)
            f32x4 s[4] = {z4, z4, z4, z4};
            #pragma unroll
            for (int nt = 0; nt < 4; nt++) {
                const int krow = nt * 16 + lr;
                const int sw   = (krow & 7) << 3;
                const short8 kf0 = *(const short8*)&Ks[krow * 64 + ((lk * 8) ^ sw)];
                const short8 kf1 = *(const short8*)&Ks[krow * 64 + ((32 + lk * 8) ^ sw)];
                s[nt] = __builtin_amdgcn_mfma_f32_16x16x32_bf16(kf0, qf0, s[nt], 0, 0, 0);
                s[nt] = __builtin_amdgcn_mfma_f32_16x16x32_bf16(kf1, qf1, s[nt], 0, 0, 0);
            }

            if (kb == T) {
                #pragma unroll
                for (int nt = 0; nt < 4; nt++)
                    #pragma unroll
                    for (int g = 0; g < 4; g++)
                        if (nt * 16 + lk * 4 + g > wv * 16 + lr) s[nt][g] = -3.0e38f;
            }

            // tile max for q-row lr
            float mx = -3.0e38f;
            #pragma unroll
            for (int nt = 0; nt < 4; nt++)
                #pragma unroll
                for (int g = 0; g < 4; g++) mx = fmaxf(mx, s[nt][g]);
            mx = fmaxf(mx, __shfl_xor(mx, 16));
            mx = fmaxf(mx, __shfl_xor(mx, 32));

            // defer-max: only rescale when some row's max grew past threshold
            float corr = 1.0f;
            if (__any(mx > mrun + 11.0f)) {
                const float mn = fmaxf(mrun, mx);
                corr = fexp2(mrun - mn);
                mrun = mn;
                #pragma unroll
                for (int g = 0; g < 4; g++) {
                    const float cg = __shfl(corr, lk * 4 + g);
                    #pragma unroll
                    for (int dt = 0; dt < 4; dt++) o[dt][g] *= cg;
                }
            }

            float pp[4][4];
            float rs = 0.f;
            #pragma unroll
            for (int nt = 0; nt < 4; nt++)
                #pragma unroll
                for (int g = 0; g < 4; g++) { pp[nt][g] = fexp2(s[nt][g] - mrun); rs += pp[nt][g]; }
            rs += __shfl_xor(rs, 16);
            rs += __shfl_xor(rs, 32);
            lrun = lrun * corr + rs;

            // P[q=lr][key] packed u32, swizzle keyed on row lr
            const int psw = (lr & 7) << 3;
            #pragma unroll
            for (int nt = 0; nt < 4; nt++) {
                const int c0 = (nt * 16 + lk * 4) ^ psw;
                *(unsigned int*)&Ps[wv][lr * 64 + c0]     = pk2(pp[nt][0], pp[nt][1]);
                *(unsigned int*)&Ps[wv][lr * 64 + c0 + 2] = pk2(pp[nt][2], pp[nt][3]);
            }
            asm volatile("s_waitcnt lgkmcnt(0)" ::: "memory");

            // O += P V
            #pragma unroll
            for (int ks = 0; ks < 2; ks++) {
                const short8 pf = *(const short8*)&Ps[wv][lr * 64 + ((ks * 32 + lk * 8) ^ psw)];
                #pragma unroll
                for (int dt = 0; dt < 4; dt++) {
                    const int vrow = dt * 16 + lr;
                    const short8 vf = *(const short8*)&Vs[vrow * 64 + ((ks * 32 + lk * 8) ^ psw)];
                    o[dt] = __builtin_amdgcn_mfma_f32_16x16x32_bf16(pf, vf, o[dt], 0, 0, 0);
                }
            }
        }

        // epilogue: bf16 out (B, S, NH*HD)
        #pragma unroll
        for (int g = 0; g < 4; g++) {
            const int qr = q0 + wv * 16 + lk * 4 + g;
            const float lg  = __shfl(lrun, lk * 4 + g);
            const float inv = 1.0f / lg;
            unsigned short* op = &out[((size_t)(b * SEQ + qr)) * HID + h * HD + lr];
            op[0]  = f2b(o[0][g] * inv);
            op[16] = f2b(o[1][g] * inv);
            op[32] = f2b(o[2][g] * inv);
            op[48] = f2b(o[3][g] * inv);
        }
    }
}

// ---------------------------------------------------------------------------
// Output projection, bf16 MFMA (validated Round 8).
// ---------------------------------------------------------------------------
__global__ __launch_bounds__(256)
void proj_mfma(const unsigned short* __restrict__ Ab,
               const unsigned short* __restrict__ Bt,
               const float* __restrict__ bias, float* __restrict__ out)
{
    __shared__ unsigned short As[128 * 64];
    __shared__ unsigned short Bs[64 * 64];

    const int tid  = threadIdx.x;
    const int lane = tid & 63;
    const int wid  = tid >> 6;
    const int wr   = wid >> 1, wc = wid & 1;
    const int lr   = lane & 15, lk = lane >> 4;
    const int bm   = blockIdx.x * 128;
    const int bn   = blockIdx.y * 64;

    const f32x4 z4 = {0.f, 0.f, 0.f, 0.f};
    f32x4 acc[4][2];
    #pragma unroll
    for (int m = 0; m < 4; m++) { acc[m][0] = z4; acc[m][1] = z4; }

    for (int kt = 0; kt < HID / 64; kt++) {
        __syncthreads();
        #pragma unroll
        for (int it = 0; it < 4; it++) {
            const int ch = tid + it * 256;
            const int row = ch >> 3, slot = ch & 7;
            *(short8*)&As[row * 64 + ((slot ^ (row & 7)) << 3)] =
                *(const short8*)&Ab[(size_t)(bm + row) * HID + kt * 64 + slot * 8];
        }
        #pragma unroll
        for (int it = 0; it < 2; it++) {
            const int ch = tid + it * 256;
            const int row = ch >> 3, slot = ch & 7;
            *(short8*)&Bs[row * 64 + ((slot ^ (row & 7)) << 3)] =
                *(const short8*)&Bt[(size_t)(bn + row) * HID + kt * 64 + slot * 8];
        }
        __syncthreads();
        const int sw = (lr & 7) << 3;
        #pragma unroll
        for (int ks = 0; ks < 2; ks++) {
            short8 bfr[2], afr[4];
            #pragma unroll
            for (int n = 0; n < 2; n++)
                bfr[n] = *(const short8*)&Bs[(wc * 32 + n * 16 + lr) * 64 + ((ks * 32 + lk * 8) ^ sw)];
            #pragma unroll
            for (int m = 0; m < 4; m++)
                afr[m] = *(const short8*)&As[(wr * 64 + m * 16 + lr) * 64 + ((ks * 32 + lk * 8) ^ sw)];
            #pragma unroll
            for (int m = 0; m < 4; m++)
                #pragma unroll
                for (int n = 0; n < 2; n++)
                    acc[m][n] = __builtin_amdgcn_mfma_f32_16x16x32_bf16(afr[m], bfr[n], acc[m][n], 0, 0, 0);
        }
    }

    #pragma unroll
    for (int m = 0; m < 4; m++) {
        #pragma unroll
        for (int g = 0; g < 4; g++) {
            const int mrow = bm + wr * 64 + m * 16 + lk * 4 + g;
            #pragma unroll
            for (int n = 0; n < 2; n++) {
                const int ncol = bn + wc * 32 + n * 16 + lr;
                out[(size_t)mrow * HID + ncol] = acc[m][n][g] + bias[ncol];
            }
        }
    }
}

// ---------------------------------------------------------------------------
extern "C" void kernel_launch(void* const* d_in, const int* in_sizes, int n_in,
                              void* d_out, int out_size, void* d_ws, size_t ws_size,
                              hipStream_t stream)
{
    const float* ctx = (const float*)d_in[0];
    const float* Wq  = (const float*)d_in[1];
    const float* bq  = (const float*)d_in[2];
    const float* Wk  = (const float*)d_in[3];
    const float* bk  = (const float*)d_in[4];
    const float* Wv  = (const float*)d_in[5];
    const float* bv  = (const float*)d_in[6];
    const float* Wd  = (const float*)d_in[7];
    const float* bd  = (const float*)d_in[8];
    float* outp = (float*)d_out;

    // workspace layout (41 MB), all bf16:
    //   [0,4MB)    ctxb [4096x512]
    //   [4,5MB)    wqt  [1024x512]   [5,6MB) wkt   [6,7MB) wvt
    //   [7,9MB)    wdt  [1024x1024]
    //   [9,17MB)   qb   [b,h,s,d]    [17,25MB) kb  [b,h,s,d]
    //   [25,33MB)  vt   [b,h,d,s]    (written directly by qkv_mfma)
    //   [33,41MB)  aw   [4096x1024]
    char* w = (char*)d_ws;
    unsigned short* ctxb = (unsigned short*)(w);
    unsigned short* wqt  = (unsigned short*)(w + (size_t)4  * 1024 * 1024);
    unsigned short* wkt  = (unsigned short*)(w + (size_t)5  * 1024 * 1024);
    unsigned short* wvt  = (unsigned short*)(w + (size_t)6  * 1024 * 1024);
    unsigned short* wdt  = (unsigned short*)(w + (size_t)7  * 1024 * 1024);
    unsigned short* qb   = (unsigned short*)(w + (size_t)9  * 1024 * 1024);
    unsigned short* kb   = (unsigned short*)(w + (size_t)17 * 1024 * 1024);
    unsigned short* vt   = (unsigned short*)(w + (size_t)25 * 1024 * 1024);
    unsigned short* aw   = (unsigned short*)(w + (size_t)33 * 1024 * 1024);

    const dim3 blk(256);
    pack4    <<<dim3(16, 16, 5),  blk, 0, stream>>>(Wq, Wk, Wv, Wd, ctx, wqt, wkt, wvt, wdt, ctxb);
    qkv_mfma <<<dim3(32, 16, 3),  blk, 0, stream>>>(ctxb, wqt, wkt, wvt, bq, bk, bv, qb, kb, vt);
    rope_bf16<<<dim3(4096),       blk, 0, stream>>>(qb, kb);
    attn_mfma<<<dim3(16, NH, NB), blk, 0, stream>>>(qb, kb, vt, aw);
    proj_mfma<<<dim3(32, 16),     blk, 0, stream>>>(aw, wdt, bd, outp);
}